// Round 1
// baseline (353.969 us; speedup 1.0000x reference)
//
#include <hip/hip_runtime.h>
#include <hip/hip_bf16.h>

#define NN 50000
#define NE 800000
#define D 128
#define NEG_SLOPE 0.01f
#define LN_EPS 1e-5f

// ---------------- CSR build ----------------

__global__ void deg_kernel(const int* __restrict__ dst, int* __restrict__ deg, int ne) {
    int e = blockIdx.x * blockDim.x + threadIdx.x;
    if (e < ne) atomicAdd(&deg[dst[e]], 1);
}

__global__ void dinv_kernel(const int* __restrict__ deg, float* __restrict__ dinv, int n) {
    int i = blockIdx.x * blockDim.x + threadIdx.x;
    if (i < n) dinv[i] = rsqrtf((float)(deg[i] + 1));  // +1: self-loop
}

// Hillis-Steele block scan; writes per-element exclusive prefix and block total.
__global__ void scan_block(const int* __restrict__ in, int* __restrict__ out_excl,
                           int* __restrict__ blocksum, int n) {
    __shared__ int tmp[256];
    int t = threadIdx.x, b = blockIdx.x, i = b * 256 + t;
    int v = (i < n) ? in[i] : 0;
    tmp[t] = v;
    __syncthreads();
    for (int off = 1; off < 256; off <<= 1) {
        int u = (t >= off) ? tmp[t - off] : 0;
        __syncthreads();
        tmp[t] += u;
        __syncthreads();
    }
    if (i < n) out_excl[i] = tmp[t] - v;
    if (t == 255) blocksum[b] = tmp[255];
}

__global__ void scan_combine(const int* __restrict__ rowtmp, const int* __restrict__ blockoff,
                             int* __restrict__ rowstart, int n, int ne) {
    int i = blockIdx.x * 256 + threadIdx.x;
    if (i < n) rowstart[i] = rowtmp[i] + blockoff[i >> 8];
    if (i == 0) rowstart[n] = ne;
}

__global__ void scatter_kernel(const int* __restrict__ src, const int* __restrict__ dst,
                               const float* __restrict__ dinv, const int* __restrict__ rowstart,
                               int* __restrict__ cursor, int* __restrict__ csr_src,
                               float* __restrict__ csr_coef, int ne) {
    int e = blockIdx.x * blockDim.x + threadIdx.x;
    if (e < ne) {
        int s = src[e], d = dst[e];
        int pos = rowstart[d] + atomicAdd(&cursor[d], 1);
        csr_src[pos] = s;
        csr_coef[pos] = dinv[s] * dinv[d];
    }
}

// ---------------- GEMM: out[n x 128] = A[n x 128] @ W[128 x 128] ----------------
// 64-row tile per block, 256 threads: thread (rg=t>>5, jg=t&31) computes
// rows rg*8..rg*8+7, cols jg*4..jg*4+3. A tile staged in LDS (32 KB); W read
// from global (64 KB, L2-resident, wave-broadcast access).
__global__ __launch_bounds__(256) void gemm128(const float* __restrict__ A,
                                               const float* __restrict__ W,
                                               float* __restrict__ out, int n) {
    __shared__ float x_lds[64 * 128];
    int t = threadIdx.x;
    int m0 = blockIdx.x * 64;
    #pragma unroll
    for (int it = 0; it < 8; ++it) {
        int idx = t + it * 256;
        int row = idx >> 5, kq = idx & 31;
        float4 v = make_float4(0.f, 0.f, 0.f, 0.f);
        if (m0 + row < n) v = *(const float4*)&A[(size_t)(m0 + row) * D + kq * 4];
        *(float4*)&x_lds[row * D + kq * 4] = v;
    }
    __syncthreads();

    int jg = t & 31, rg = t >> 5;
    int j0 = jg * 4, r0 = rg * 8;
    float acc[8][4] = {};
    #pragma unroll 4
    for (int k = 0; k < 128; ++k) {
        float4 wv = *(const float4*)&W[k * D + j0];
        #pragma unroll
        for (int r = 0; r < 8; ++r) {
            float xv = x_lds[(r0 + r) * D + k];  // broadcast within 32-lane group
            acc[r][0] = fmaf(xv, wv.x, acc[r][0]);
            acc[r][1] = fmaf(xv, wv.y, acc[r][1]);
            acc[r][2] = fmaf(xv, wv.z, acc[r][2]);
            acc[r][3] = fmaf(xv, wv.w, acc[r][3]);
        }
    }
    #pragma unroll
    for (int r = 0; r < 8; ++r) {
        int row = m0 + r0 + r;
        if (row < n) {
            float4 o = make_float4(acc[r][0], acc[r][1], acc[r][2], acc[r][3]);
            *(float4*)&out[(size_t)row * D + j0] = o;
        }
    }
}

// ---------------- fused aggregate + bias + (leaky) + residual + LayerNorm ----------------
// MODE 0: layer1  -> out = LN1(leaky(agg + b1) + x)
// MODE 1: layer2  -> out = leaky(LN2(agg + b2 + x))
template <int MODE>
__global__ __launch_bounds__(128) void agg_ln(const float* __restrict__ h,
                                              const float* __restrict__ x,
                                              const float* __restrict__ bias,
                                              const float* __restrict__ gamma,
                                              const float* __restrict__ beta,
                                              const float* __restrict__ dinv,
                                              const int* __restrict__ rowstart,
                                              const int* __restrict__ csr_src,
                                              const float* __restrict__ csr_coef,
                                              float* __restrict__ out) {
    int i = blockIdx.x;
    int d = threadIdx.x;
    float di = dinv[i];
    float acc = di * di * h[(size_t)i * D + d];  // self-loop term
    int e0 = rowstart[i], e1 = rowstart[i + 1];
    for (int e = e0; e < e1; ++e) {
        int s = csr_src[e];
        float c = csr_coef[e];
        acc = fmaf(c, h[(size_t)s * D + d], acc);
    }
    acc += bias[d];
    float v = (MODE == 0) ? (acc > 0.f ? acc : NEG_SLOPE * acc) : acc;
    v += x[(size_t)i * D + d];

    // LayerNorm over 128 lanes (2 waves)
    float s1 = v, s2 = v * v;
    #pragma unroll
    for (int off = 1; off < 64; off <<= 1) {
        s1 += __shfl_xor(s1, off, 64);
        s2 += __shfl_xor(s2, off, 64);
    }
    __shared__ float ws1[2], ws2[2];
    int wid = d >> 6;
    if ((d & 63) == 0) { ws1[wid] = s1; ws2[wid] = s2; }
    __syncthreads();
    float S1 = ws1[0] + ws1[1], S2 = ws2[0] + ws2[1];
    float mu = S1 * (1.f / 128.f);
    float var = fmaxf(S2 * (1.f / 128.f) - mu * mu, 0.f);
    float rs = rsqrtf(var + LN_EPS);
    float o = (v - mu) * rs * gamma[d] + beta[d];
    if (MODE == 1) o = (o > 0.f ? o : NEG_SLOPE * o);
    out[(size_t)i * D + d] = o;
}

extern "C" void kernel_launch(void* const* d_in, const int* in_sizes, int n_in,
                              void* d_out, int out_size, void* d_ws, size_t ws_size,
                              hipStream_t stream) {
    const float* x    = (const float*)d_in[0];
    const int*   ei   = (const int*)d_in[1];   // [2, NE]: row0 src, row1 dst
    const float* W1   = (const float*)d_in[2];
    const float* b1   = (const float*)d_in[3];
    const float* ln1g = (const float*)d_in[4];
    const float* ln1b = (const float*)d_in[5];
    const float* W2   = (const float*)d_in[6];
    const float* b2   = (const float*)d_in[7];
    const float* ln2g = (const float*)d_in[8];
    const float* ln2b = (const float*)d_in[9];
    float* out = (float*)d_out;

    const int* srcp = ei;
    const int* dstp = ei + NE;

    char* ws = (char*)d_ws;
    size_t p = 0;
    auto alloc = [&](size_t bytes) {
        char* r = ws + p;
        p += (bytes + 255) & ~(size_t)255;
        return r;
    };
    int*   deg      = (int*)alloc(NN * 4);
    int*   rowtmp   = (int*)alloc(NN * 4);
    int*   rowstart = (int*)alloc((NN + 1) * 4);
    int*   cursor   = (int*)alloc(NN * 4);
    int*   blocksum = (int*)alloc(256 * 4);
    int*   blockoff = (int*)alloc(256 * 4);
    int*   dummy    = (int*)alloc(256 * 4);
    float* dinv     = (float*)alloc(NN * 4);
    int*   csr_src  = (int*)alloc((size_t)NE * 4);
    float* csr_coef = (float*)alloc((size_t)NE * 4);
    float* bufA     = (float*)alloc((size_t)NN * D * 4);  // h1 then t2

    hipMemsetAsync(deg, 0, NN * 4, stream);
    hipMemsetAsync(cursor, 0, NN * 4, stream);

    deg_kernel<<<(NE + 255) / 256, 256, 0, stream>>>(dstp, deg, NE);
    dinv_kernel<<<(NN + 255) / 256, 256, 0, stream>>>(deg, dinv, NN);

    int nblk = (NN + 255) / 256;  // 196
    scan_block<<<nblk, 256, 0, stream>>>(deg, rowtmp, blocksum, NN);
    scan_block<<<1, 256, 0, stream>>>(blocksum, blockoff, dummy, nblk);
    scan_combine<<<nblk, 256, 0, stream>>>(rowtmp, blockoff, rowstart, NN, NE);

    scatter_kernel<<<(NE + 255) / 256, 256, 0, stream>>>(srcp, dstp, dinv, rowstart,
                                                         cursor, csr_src, csr_coef, NE);

    // Layer 1: h1 = x @ W1 ; out(d_out as scratch) = LN1(leaky(agg(h1)+b1) + x)
    gemm128<<<(NN + 63) / 64, 256, 0, stream>>>(x, W1, bufA, NN);
    agg_ln<0><<<NN, 128, 0, stream>>>(bufA, x, b1, ln1g, ln1b, dinv, rowstart,
                                      csr_src, csr_coef, out);

    // Layer 2: t = h2 @ W2 ; out = leaky(LN2(agg(t)+b2 + x))
    gemm128<<<(NN + 63) / 64, 256, 0, stream>>>(out, W2, bufA, NN);
    agg_ln<1><<<NN, 128, 0, stream>>>(bufA, x, b2, ln2g, ln2b, dinv, rowstart,
                                      csr_src, csr_coef, out);
}

// Round 2
// 282.377 us; speedup vs baseline: 1.2535x; 1.2535x over previous
//
#include <hip/hip_runtime.h>
#include <hip/hip_bf16.h>

#define NN 50000
#define NE 800000
#define D 128
#define NEG_SLOPE 0.01f
#define LN_EPS 1e-5f

// ---------------- CSR build ----------------

__global__ void deg_kernel(const int* __restrict__ dst, int* __restrict__ deg, int ne) {
    int e = blockIdx.x * blockDim.x + threadIdx.x;
    if (e < ne) atomicAdd(&deg[dst[e]], 1);
}

__global__ void dinv_kernel(const int* __restrict__ deg, float* __restrict__ dinv, int n) {
    int i = blockIdx.x * blockDim.x + threadIdx.x;
    if (i < n) dinv[i] = rsqrtf((float)(deg[i] + 1));  // +1: self-loop
}

// Hillis-Steele block scan; writes per-element exclusive prefix and block total.
__global__ void scan_block(const int* __restrict__ in, int* __restrict__ out_excl,
                           int* __restrict__ blocksum, int n) {
    __shared__ int tmp[256];
    int t = threadIdx.x, b = blockIdx.x, i = b * 256 + t;
    int v = (i < n) ? in[i] : 0;
    tmp[t] = v;
    __syncthreads();
    for (int off = 1; off < 256; off <<= 1) {
        int u = (t >= off) ? tmp[t - off] : 0;
        __syncthreads();
        tmp[t] += u;
        __syncthreads();
    }
    if (i < n) out_excl[i] = tmp[t] - v;
    if (t == 255) blocksum[b] = tmp[255];
}

__global__ void scan_combine(const int* __restrict__ rowtmp, const int* __restrict__ blockoff,
                             int* __restrict__ rowstart, int n, int ne) {
    int i = blockIdx.x * 256 + threadIdx.x;
    if (i < n) rowstart[i] = rowtmp[i] + blockoff[i >> 8];
    if (i == 0) rowstart[n] = ne;
}

// Writes interleaved (src, coef-bits) pairs so the hot loop does ONE 8B load per edge.
__global__ void scatter_kernel(const int* __restrict__ src, const int* __restrict__ dst,
                               const float* __restrict__ dinv, const int* __restrict__ rowstart,
                               int* __restrict__ cursor, int2* __restrict__ csr_pair, int ne) {
    int e = blockIdx.x * blockDim.x + threadIdx.x;
    if (e < ne) {
        int s = src[e], d = dst[e];
        int pos = rowstart[d] + atomicAdd(&cursor[d], 1);
        float coef = dinv[s] * dinv[d];
        csr_pair[pos] = make_int2(s, __float_as_int(coef));
    }
}

// ---------------- GEMM: out[n x 128] = A[n x 128] @ W[128 x 128] ----------------
__global__ __launch_bounds__(256) void gemm128(const float* __restrict__ A,
                                               const float* __restrict__ W,
                                               float* __restrict__ out, int n) {
    __shared__ float x_lds[64 * 128];
    int t = threadIdx.x;
    int m0 = blockIdx.x * 64;
    #pragma unroll
    for (int it = 0; it < 8; ++it) {
        int idx = t + it * 256;
        int row = idx >> 5, kq = idx & 31;
        float4 v = make_float4(0.f, 0.f, 0.f, 0.f);
        if (m0 + row < n) v = *(const float4*)&A[(size_t)(m0 + row) * D + kq * 4];
        *(float4*)&x_lds[row * D + kq * 4] = v;
    }
    __syncthreads();

    int jg = t & 31, rg = t >> 5;
    int j0 = jg * 4, r0 = rg * 8;
    float acc[8][4] = {};
    #pragma unroll 4
    for (int k = 0; k < 128; ++k) {
        float4 wv = *(const float4*)&W[k * D + j0];
        #pragma unroll
        for (int r = 0; r < 8; ++r) {
            float xv = x_lds[(r0 + r) * D + k];
            acc[r][0] = fmaf(xv, wv.x, acc[r][0]);
            acc[r][1] = fmaf(xv, wv.y, acc[r][1]);
            acc[r][2] = fmaf(xv, wv.z, acc[r][2]);
            acc[r][3] = fmaf(xv, wv.w, acc[r][3]);
        }
    }
    #pragma unroll
    for (int r = 0; r < 8; ++r) {
        int row = m0 + r0 + r;
        if (row < n) {
            float4 o = make_float4(acc[r][0], acc[r][1], acc[r][2], acc[r][3]);
            *(float4*)&out[(size_t)row * D + j0] = o;
        }
    }
}

// ---------------- fused aggregate + bias + (leaky) + residual + LayerNorm ----------------
// Wave-per-node: 64 lanes x float2 = 128 dims. 4 waves (4 nodes) per 256-thread block.
// Edge loop unrolled x4: 4 independent row-gathers in flight per wave.
// MODE 0: out = LN1(leaky(agg + b1) + x)
// MODE 1: out = leaky(LN2(agg + b2 + x))
template <int MODE>
__global__ __launch_bounds__(256) void agg_ln(const float* __restrict__ h,
                                              const float* __restrict__ x,
                                              const float* __restrict__ bias,
                                              const float* __restrict__ gamma,
                                              const float* __restrict__ beta,
                                              const float* __restrict__ dinv,
                                              const int* __restrict__ rowstart,
                                              const int2* __restrict__ csr_pair,
                                              float* __restrict__ out) {
    int wid = threadIdx.x >> 6;
    int lane = threadIdx.x & 63;
    int i = blockIdx.x * 4 + wid;   // NN = 50000 = 12500 * 4, exact
    float di = dinv[i];
    size_t rowoff = (size_t)i * D + 2 * lane;

    float2 hs = *(const float2*)&h[rowoff];
    float accx = di * di * hs.x, accy = di * di * hs.y;

    int e = rowstart[i], e1 = rowstart[i + 1];
    for (; e + 4 <= e1; e += 4) {
        int2 p0 = csr_pair[e + 0];
        int2 p1 = csr_pair[e + 1];
        int2 p2 = csr_pair[e + 2];
        int2 p3 = csr_pair[e + 3];
        float2 g0 = *(const float2*)&h[(size_t)p0.x * D + 2 * lane];
        float2 g1 = *(const float2*)&h[(size_t)p1.x * D + 2 * lane];
        float2 g2 = *(const float2*)&h[(size_t)p2.x * D + 2 * lane];
        float2 g3 = *(const float2*)&h[(size_t)p3.x * D + 2 * lane];
        float c0 = __int_as_float(p0.y), c1 = __int_as_float(p1.y);
        float c2 = __int_as_float(p2.y), c3 = __int_as_float(p3.y);
        accx = fmaf(c0, g0.x, accx); accy = fmaf(c0, g0.y, accy);
        accx = fmaf(c1, g1.x, accx); accy = fmaf(c1, g1.y, accy);
        accx = fmaf(c2, g2.x, accx); accy = fmaf(c2, g2.y, accy);
        accx = fmaf(c3, g3.x, accx); accy = fmaf(c3, g3.y, accy);
    }
    for (; e < e1; ++e) {
        int2 p = csr_pair[e];
        float2 g = *(const float2*)&h[(size_t)p.x * D + 2 * lane];
        float c = __int_as_float(p.y);
        accx = fmaf(c, g.x, accx); accy = fmaf(c, g.y, accy);
    }

    float2 bv = *(const float2*)&bias[2 * lane];
    accx += bv.x; accy += bv.y;
    if (MODE == 0) {
        accx = accx > 0.f ? accx : NEG_SLOPE * accx;
        accy = accy > 0.f ? accy : NEG_SLOPE * accy;
    }
    float2 xv = *(const float2*)&x[rowoff];
    float v0 = accx + xv.x, v1 = accy + xv.y;

    // LayerNorm over the wave (128 dims in 64 lanes x 2)
    float s1 = v0 + v1, s2 = v0 * v0 + v1 * v1;
    #pragma unroll
    for (int off = 1; off < 64; off <<= 1) {
        s1 += __shfl_xor(s1, off, 64);
        s2 += __shfl_xor(s2, off, 64);
    }
    float mu = s1 * (1.f / 128.f);
    float var = fmaxf(s2 * (1.f / 128.f) - mu * mu, 0.f);
    float rs = rsqrtf(var + LN_EPS);

    float2 gv = *(const float2*)&gamma[2 * lane];
    float2 bt = *(const float2*)&beta[2 * lane];
    float o0 = (v0 - mu) * rs * gv.x + bt.x;
    float o1 = (v1 - mu) * rs * gv.y + bt.y;
    if (MODE == 1) {
        o0 = o0 > 0.f ? o0 : NEG_SLOPE * o0;
        o1 = o1 > 0.f ? o1 : NEG_SLOPE * o1;
    }
    *(float2*)&out[rowoff] = make_float2(o0, o1);
}

extern "C" void kernel_launch(void* const* d_in, const int* in_sizes, int n_in,
                              void* d_out, int out_size, void* d_ws, size_t ws_size,
                              hipStream_t stream) {
    const float* x    = (const float*)d_in[0];
    const int*   ei   = (const int*)d_in[1];   // [2, NE]: row0 src, row1 dst
    const float* W1   = (const float*)d_in[2];
    const float* b1   = (const float*)d_in[3];
    const float* ln1g = (const float*)d_in[4];
    const float* ln1b = (const float*)d_in[5];
    const float* W2   = (const float*)d_in[6];
    const float* b2   = (const float*)d_in[7];
    const float* ln2g = (const float*)d_in[8];
    const float* ln2b = (const float*)d_in[9];
    float* out = (float*)d_out;

    const int* srcp = ei;
    const int* dstp = ei + NE;

    char* ws = (char*)d_ws;
    size_t p = 0;
    auto alloc = [&](size_t bytes) {
        char* r = ws + p;
        p += (bytes + 255) & ~(size_t)255;
        return r;
    };
    int*   deg      = (int*)alloc(NN * 4);
    int*   rowtmp   = (int*)alloc(NN * 4);
    int*   rowstart = (int*)alloc((NN + 1) * 4);
    int*   cursor   = (int*)alloc(NN * 4);
    int*   blocksum = (int*)alloc(256 * 4);
    int*   blockoff = (int*)alloc(256 * 4);
    int*   dummy    = (int*)alloc(256 * 4);
    float* dinv     = (float*)alloc(NN * 4);
    int2*  csr_pair = (int2*)alloc((size_t)NE * 8);
    float* bufA     = (float*)alloc((size_t)NN * D * 4);  // h1 then t2

    hipMemsetAsync(deg, 0, NN * 4, stream);
    hipMemsetAsync(cursor, 0, NN * 4, stream);

    deg_kernel<<<(NE + 255) / 256, 256, 0, stream>>>(dstp, deg, NE);
    dinv_kernel<<<(NN + 255) / 256, 256, 0, stream>>>(deg, dinv, NN);

    int nblk = (NN + 255) / 256;  // 196
    scan_block<<<nblk, 256, 0, stream>>>(deg, rowtmp, blocksum, NN);
    scan_block<<<1, 256, 0, stream>>>(blocksum, blockoff, dummy, nblk);
    scan_combine<<<nblk, 256, 0, stream>>>(rowtmp, blockoff, rowstart, NN, NE);

    scatter_kernel<<<(NE + 255) / 256, 256, 0, stream>>>(srcp, dstp, dinv, rowstart,
                                                         cursor, csr_pair, NE);

    // Layer 1: h1 = x @ W1 ; out(d_out as scratch) = LN1(leaky(agg(h1)+b1) + x)
    gemm128<<<(NN + 63) / 64, 256, 0, stream>>>(x, W1, bufA, NN);
    agg_ln<0><<<NN / 4, 256, 0, stream>>>(bufA, x, b1, ln1g, ln1b, dinv, rowstart,
                                          csr_pair, out);

    // Layer 2: t = h2 @ W2 ; out = leaky(LN2(agg(t)+b2 + x))
    gemm128<<<(NN + 63) / 64, 256, 0, stream>>>(out, W2, bufA, NN);
    agg_ln<1><<<NN / 4, 256, 0, stream>>>(bufA, x, b2, ln2g, ln2b, dinv, rowstart,
                                          csr_pair, out);
}

// Round 3
// 243.559 us; speedup vs baseline: 1.4533x; 1.1594x over previous
//
#include <hip/hip_runtime.h>
#include <hip/hip_bf16.h>

#define NN 50000
#define NE 800000
#define D 128
#define NEG_SLOPE 0.01f
#define LN_EPS 1e-5f

// f32 -> bf16 round-to-nearest-even (finite values)
__device__ inline unsigned short f2bf(float f) {
    unsigned u = __float_as_uint(f);
    unsigned r = 0x7FFFu + ((u >> 16) & 1u);
    return (unsigned short)((u + r) >> 16);
}
// unpack one dword = 2 bf16 -> 2 floats
__device__ inline void bf2x(unsigned u, float& lo, float& hi) {
    lo = __uint_as_float(u << 16);
    hi = __uint_as_float(u & 0xFFFF0000u);
}

// ---------------- CSR build ----------------

__global__ void deg_kernel(const int* __restrict__ dst, int* __restrict__ deg, int ne) {
    int e = blockIdx.x * blockDim.x + threadIdx.x;
    if (e < ne) atomicAdd(&deg[dst[e]], 1);
}

__global__ void dinv_kernel(const int* __restrict__ deg, float* __restrict__ dinv, int n) {
    int i = blockIdx.x * blockDim.x + threadIdx.x;
    if (i < n) dinv[i] = rsqrtf((float)(deg[i] + 1));  // +1: self-loop
}

__global__ void scan_block(const int* __restrict__ in, int* __restrict__ out_excl,
                           int* __restrict__ blocksum, int n) {
    __shared__ int tmp[256];
    int t = threadIdx.x, b = blockIdx.x, i = b * 256 + t;
    int v = (i < n) ? in[i] : 0;
    tmp[t] = v;
    __syncthreads();
    for (int off = 1; off < 256; off <<= 1) {
        int u = (t >= off) ? tmp[t - off] : 0;
        __syncthreads();
        tmp[t] += u;
        __syncthreads();
    }
    if (i < n) out_excl[i] = tmp[t] - v;
    if (t == 255) blocksum[b] = tmp[255];
}

__global__ void scan_combine(const int* __restrict__ rowtmp, const int* __restrict__ blockoff,
                             int* __restrict__ rowstart, int n, int ne) {
    int i = blockIdx.x * 256 + threadIdx.x;
    if (i < n) rowstart[i] = rowtmp[i] + blockoff[i >> 8];
    if (i == 0) rowstart[n] = ne;
}

// Interleaved (src, coef-bits): ONE 8B load per edge in the hot loop.
__global__ void scatter_kernel(const int* __restrict__ src, const int* __restrict__ dst,
                               const float* __restrict__ dinv, const int* __restrict__ rowstart,
                               int* __restrict__ cursor, int2* __restrict__ csr_pair, int ne) {
    int e = blockIdx.x * blockDim.x + threadIdx.x;
    if (e < ne) {
        int s = src[e], d = dst[e];
        int pos = rowstart[d] + atomicAdd(&cursor[d], 1);
        float coef = dinv[s] * dinv[d];
        csr_pair[pos] = make_int2(s, __float_as_int(coef));
    }
}

// ---------------- GEMM: out_bf16[n x 128] = A[n x 128] @ W[128 x 128] ----------------
// f32 math, bf16 output (the aggregation gather table).
__global__ __launch_bounds__(256) void gemm128(const float* __restrict__ A,
                                               const float* __restrict__ W,
                                               unsigned short* __restrict__ out, int n) {
    __shared__ float x_lds[64 * 128];
    int t = threadIdx.x;
    int m0 = blockIdx.x * 64;
    #pragma unroll
    for (int it = 0; it < 8; ++it) {
        int idx = t + it * 256;
        int row = idx >> 5, kq = idx & 31;
        float4 v = make_float4(0.f, 0.f, 0.f, 0.f);
        if (m0 + row < n) v = *(const float4*)&A[(size_t)(m0 + row) * D + kq * 4];
        *(float4*)&x_lds[row * D + kq * 4] = v;
    }
    __syncthreads();

    int jg = t & 31, rg = t >> 5;
    int j0 = jg * 4, r0 = rg * 8;
    float acc[8][4] = {};
    #pragma unroll 4
    for (int k = 0; k < 128; ++k) {
        float4 wv = *(const float4*)&W[k * D + j0];
        #pragma unroll
        for (int r = 0; r < 8; ++r) {
            float xv = x_lds[(r0 + r) * D + k];
            acc[r][0] = fmaf(xv, wv.x, acc[r][0]);
            acc[r][1] = fmaf(xv, wv.y, acc[r][1]);
            acc[r][2] = fmaf(xv, wv.z, acc[r][2]);
            acc[r][3] = fmaf(xv, wv.w, acc[r][3]);
        }
    }
    #pragma unroll
    for (int r = 0; r < 8; ++r) {
        int row = m0 + r0 + r;
        if (row < n) {
            ushort4 o;
            o.x = f2bf(acc[r][0]); o.y = f2bf(acc[r][1]);
            o.z = f2bf(acc[r][2]); o.w = f2bf(acc[r][3]);
            *(ushort4*)&out[(size_t)row * D + j0] = o;
        }
    }
}

// ---------------- fused aggregate + bias + (leaky) + residual + LayerNorm ----------------
// Wave-per-node, gather table h in bf16 (one dword = 2 dims per lane per edge).
// MODE 0: out = LN1(leaky(agg + b1) + x)
// MODE 1: out = leaky(LN2(agg + b2 + x))
template <int MODE>
__global__ __launch_bounds__(256) void agg_ln(const unsigned* __restrict__ h,  // bf16x2 per dword
                                              const float* __restrict__ x,
                                              const float* __restrict__ bias,
                                              const float* __restrict__ gamma,
                                              const float* __restrict__ beta,
                                              const float* __restrict__ dinv,
                                              const int* __restrict__ rowstart,
                                              const int2* __restrict__ csr_pair,
                                              float* __restrict__ out) {
    int wid = threadIdx.x >> 6;
    int lane = threadIdx.x & 63;
    int i = blockIdx.x * 4 + wid;   // NN = 50000 = 12500 * 4, exact
    float di = dinv[i];
    size_t rowoff = (size_t)i * D + 2 * lane;   // f32 index (x / out)
    size_t bfoff = (size_t)i * (D / 2) + lane;  // dword index into h

    float hx, hy;
    bf2x(h[bfoff], hx, hy);
    float accx = di * di * hx, accy = di * di * hy;

    int e = rowstart[i], e1 = rowstart[i + 1];
    for (; e + 4 <= e1; e += 4) {
        int2 p0 = csr_pair[e + 0];
        int2 p1 = csr_pair[e + 1];
        int2 p2 = csr_pair[e + 2];
        int2 p3 = csr_pair[e + 3];
        unsigned g0 = h[(size_t)p0.x * (D / 2) + lane];
        unsigned g1 = h[(size_t)p1.x * (D / 2) + lane];
        unsigned g2 = h[(size_t)p2.x * (D / 2) + lane];
        unsigned g3 = h[(size_t)p3.x * (D / 2) + lane];
        float c0 = __int_as_float(p0.y), c1 = __int_as_float(p1.y);
        float c2 = __int_as_float(p2.y), c3 = __int_as_float(p3.y);
        float ax, ay;
        bf2x(g0, ax, ay); accx = fmaf(c0, ax, accx); accy = fmaf(c0, ay, accy);
        bf2x(g1, ax, ay); accx = fmaf(c1, ax, accx); accy = fmaf(c1, ay, accy);
        bf2x(g2, ax, ay); accx = fmaf(c2, ax, accx); accy = fmaf(c2, ay, accy);
        bf2x(g3, ax, ay); accx = fmaf(c3, ax, accx); accy = fmaf(c3, ay, accy);
    }
    for (; e < e1; ++e) {
        int2 p = csr_pair[e];
        unsigned g = h[(size_t)p.x * (D / 2) + lane];
        float c = __int_as_float(p.y);
        float ax, ay;
        bf2x(g, ax, ay);
        accx = fmaf(c, ax, accx); accy = fmaf(c, ay, accy);
    }

    float2 bv = *(const float2*)&bias[2 * lane];
    accx += bv.x; accy += bv.y;
    if (MODE == 0) {
        accx = accx > 0.f ? accx : NEG_SLOPE * accx;
        accy = accy > 0.f ? accy : NEG_SLOPE * accy;
    }
    float2 xv = *(const float2*)&x[rowoff];
    float v0 = accx + xv.x, v1 = accy + xv.y;

    float s1 = v0 + v1, s2 = v0 * v0 + v1 * v1;
    #pragma unroll
    for (int off = 1; off < 64; off <<= 1) {
        s1 += __shfl_xor(s1, off, 64);
        s2 += __shfl_xor(s2, off, 64);
    }
    float mu = s1 * (1.f / 128.f);
    float var = fmaxf(s2 * (1.f / 128.f) - mu * mu, 0.f);
    float rs = rsqrtf(var + LN_EPS);

    float2 gv = *(const float2*)&gamma[2 * lane];
    float2 bt = *(const float2*)&beta[2 * lane];
    float o0 = (v0 - mu) * rs * gv.x + bt.x;
    float o1 = (v1 - mu) * rs * gv.y + bt.y;
    if (MODE == 1) {
        o0 = o0 > 0.f ? o0 : NEG_SLOPE * o0;
        o1 = o1 > 0.f ? o1 : NEG_SLOPE * o1;
    }
    *(float2*)&out[rowoff] = make_float2(o0, o1);
}

extern "C" void kernel_launch(void* const* d_in, const int* in_sizes, int n_in,
                              void* d_out, int out_size, void* d_ws, size_t ws_size,
                              hipStream_t stream) {
    const float* x    = (const float*)d_in[0];
    const int*   ei   = (const int*)d_in[1];   // [2, NE]: row0 src, row1 dst
    const float* W1   = (const float*)d_in[2];
    const float* b1   = (const float*)d_in[3];
    const float* ln1g = (const float*)d_in[4];
    const float* ln1b = (const float*)d_in[5];
    const float* W2   = (const float*)d_in[6];
    const float* b2   = (const float*)d_in[7];
    const float* ln2g = (const float*)d_in[8];
    const float* ln2b = (const float*)d_in[9];
    float* out = (float*)d_out;

    const int* srcp = ei;
    const int* dstp = ei + NE;

    char* ws = (char*)d_ws;
    size_t p = 0;
    auto alloc = [&](size_t bytes) {
        char* r = ws + p;
        p += (bytes + 255) & ~(size_t)255;
        return r;
    };
    int*   deg      = (int*)alloc(NN * 4);
    int*   rowtmp   = (int*)alloc(NN * 4);
    int*   rowstart = (int*)alloc((NN + 1) * 4);
    int*   cursor   = (int*)alloc(NN * 4);
    int*   blocksum = (int*)alloc(256 * 4);
    int*   blockoff = (int*)alloc(256 * 4);
    int*   dummy    = (int*)alloc(256 * 4);
    float* dinv     = (float*)alloc(NN * 4);
    int2*  csr_pair = (int2*)alloc((size_t)NE * 8);
    unsigned short* hbf = (unsigned short*)alloc((size_t)NN * D * 2);  // bf16 gather table

    hipMemsetAsync(deg, 0, NN * 4, stream);
    hipMemsetAsync(cursor, 0, NN * 4, stream);

    deg_kernel<<<(NE + 255) / 256, 256, 0, stream>>>(dstp, deg, NE);
    dinv_kernel<<<(NN + 255) / 256, 256, 0, stream>>>(deg, dinv, NN);

    int nblk = (NN + 255) / 256;  // 196
    scan_block<<<nblk, 256, 0, stream>>>(deg, rowtmp, blocksum, NN);
    scan_block<<<1, 256, 0, stream>>>(blocksum, blockoff, dummy, nblk);
    scan_combine<<<nblk, 256, 0, stream>>>(rowtmp, blockoff, rowstart, NN, NE);

    scatter_kernel<<<(NE + 255) / 256, 256, 0, stream>>>(srcp, dstp, dinv, rowstart,
                                                         cursor, csr_pair, NE);

    // Layer 1: h1 = bf16(x @ W1) ; out = LN1(leaky(agg(h1)+b1) + x)
    gemm128<<<(NN + 63) / 64, 256, 0, stream>>>(x, W1, hbf, NN);
    agg_ln<0><<<NN / 4, 256, 0, stream>>>((const unsigned*)hbf, x, b1, ln1g, ln1b, dinv,
                                          rowstart, csr_pair, out);

    // Layer 2: t = bf16(out @ W2) ; out = leaky(LN2(agg(t)+b2 + x))
    gemm128<<<(NN + 63) / 64, 256, 0, stream>>>(out, W2, hbf, NN);
    agg_ln<1><<<NN / 4, 256, 0, stream>>>((const unsigned*)hbf, x, b2, ln2g, ln2b, dinv,
                                          rowstart, csr_pair, out);
}

// Round 4
// 198.319 us; speedup vs baseline: 1.7848x; 1.2281x over previous
//
#include <hip/hip_runtime.h>
#include <hip/hip_bf16.h>

#define NN 50000
#define NE 800000
#define D 128
#define NEG_SLOPE 0.01f
#define LN_EPS 1e-5f

typedef __attribute__((ext_vector_type(8))) short bf16x8;
typedef __attribute__((ext_vector_type(4))) float f32x4;

// f32 -> bf16 round-to-nearest-even (finite values)
__device__ inline unsigned short f2bf(float f) {
    unsigned u = __float_as_uint(f);
    unsigned r = 0x7FFFu + ((u >> 16) & 1u);
    return (unsigned short)((u + r) >> 16);
}
// unpack one dword = 2 bf16 -> 2 floats
__device__ inline void bf2x(unsigned u, float& lo, float& hi) {
    lo = __uint_as_float(u << 16);
    hi = __uint_as_float(u & 0xFFFF0000u);
}

// ---------------- CSR build ----------------

__global__ void deg_kernel(const int* __restrict__ dst, int* __restrict__ deg, int ne) {
    int e = blockIdx.x * blockDim.x + threadIdx.x;
    if (e < ne) atomicAdd(&deg[dst[e]], 1);
}

__global__ void dinv_kernel(const int* __restrict__ deg, float* __restrict__ dinv, int n) {
    int i = blockIdx.x * blockDim.x + threadIdx.x;
    if (i < n) dinv[i] = rsqrtf((float)(deg[i] + 1));  // +1: self-loop
}

__global__ void scan_block(const int* __restrict__ in, int* __restrict__ out_excl,
                           int* __restrict__ blocksum, int n) {
    __shared__ int tmp[256];
    int t = threadIdx.x, b = blockIdx.x, i = b * 256 + t;
    int v = (i < n) ? in[i] : 0;
    tmp[t] = v;
    __syncthreads();
    for (int off = 1; off < 256; off <<= 1) {
        int u = (t >= off) ? tmp[t - off] : 0;
        __syncthreads();
        tmp[t] += u;
        __syncthreads();
    }
    if (i < n) out_excl[i] = tmp[t] - v;
    if (t == 255) blocksum[b] = tmp[255];
}

__global__ void scan_combine(const int* __restrict__ rowtmp, const int* __restrict__ blockoff,
                             int* __restrict__ rowstart, int n, int ne) {
    int i = blockIdx.x * 256 + threadIdx.x;
    if (i < n) rowstart[i] = rowtmp[i] + blockoff[i >> 8];
    if (i == 0) rowstart[n] = ne;
}

// Interleaved (src, coef-bits): ONE 8B load per edge in the hot loop.
__global__ void scatter_kernel(const int* __restrict__ src, const int* __restrict__ dst,
                               const float* __restrict__ dinv, const int* __restrict__ rowstart,
                               int* __restrict__ cursor, int2* __restrict__ csr_pair, int ne) {
    int e = blockIdx.x * blockDim.x + threadIdx.x;
    if (e < ne) {
        int s = src[e], d = dst[e];
        int pos = rowstart[d] + atomicAdd(&cursor[d], 1);
        float coef = dinv[s] * dinv[d];
        csr_pair[pos] = make_int2(s, __float_as_int(coef));
    }
}

// W [128][128] f32 (W[k][n]) -> WT [128][128] bf16 (WT[n][k])
__global__ void wt_pack(const float* __restrict__ W, unsigned short* __restrict__ WT) {
    int tid = blockIdx.x * 256 + threadIdx.x;
    int nn = tid & 127, k = tid >> 7;
    WT[nn * 128 + k] = f2bf(W[k * 128 + nn]);
}

// ---------------- MFMA GEMM: out_bf16[n x 128] = bf16(A[n x 128]) @ WT^T ----------------
// 64-row tile, 4 waves; wave w -> rows w*16..w*16+15, all 128 cols (8 N-frags).
// A and WT staged in LDS with XOR swizzle (byte ^= (row&7)<<4) for conflict-free ds_read_b128.
__global__ __launch_bounds__(256) void gemm_mfma(const float* __restrict__ A,
                                                 const unsigned short* __restrict__ WT,  // [n][k] bf16
                                                 unsigned short* __restrict__ out, int n) {
    __shared__ __align__(16) unsigned short a_lds[64 * 128];   // 16 KB
    __shared__ __align__(16) unsigned short w_lds[128 * 128];  // 32 KB
    int t = threadIdx.x;
    int m0 = blockIdx.x * 64;

    // stage WT (bf16 copy, 16B chunks; 16 chunks per 128-elem row)
    #pragma unroll
    for (int it = 0; it < 8; ++it) {
        int idx = it * 256 + t;
        int row = idx >> 4, c = idx & 15;
        uint4 v = *(const uint4*)&WT[row * 128 + c * 8];
        int byte = (row * 256 + c * 16) ^ ((row & 7) << 4);
        *(uint4*)((char*)w_lds + byte) = v;
    }
    // stage A rows (f32 -> bf16), 8 floats per thread-chunk
    #pragma unroll
    for (int it = 0; it < 4; ++it) {
        int idx = it * 256 + t;
        int row = idx >> 4, c = idx & 15;
        int grow = m0 + row;
        float4 v0 = make_float4(0.f, 0.f, 0.f, 0.f), v1 = v0;
        if (grow < n) {
            v0 = *(const float4*)&A[(size_t)grow * D + c * 8];
            v1 = *(const float4*)&A[(size_t)grow * D + c * 8 + 4];
        }
        uint2 lo, hi;
        lo.x = (unsigned)f2bf(v0.x) | ((unsigned)f2bf(v0.y) << 16);
        lo.y = (unsigned)f2bf(v0.z) | ((unsigned)f2bf(v0.w) << 16);
        hi.x = (unsigned)f2bf(v1.x) | ((unsigned)f2bf(v1.y) << 16);
        hi.y = (unsigned)f2bf(v1.z) | ((unsigned)f2bf(v1.w) << 16);
        int byte = (row * 256 + c * 16) ^ ((row & 7) << 4);
        *(uint4*)((char*)a_lds + byte) = make_uint4(lo.x, lo.y, hi.x, hi.y);
    }
    __syncthreads();

    int wv = t >> 6, l = t & 63;
    int lrow = l & 15, lgrp = l >> 4;
    int arow = wv * 16 + lrow;

    f32x4 acc[8];
    #pragma unroll
    for (int nf = 0; nf < 8; ++nf) acc[nf] = (f32x4){0.f, 0.f, 0.f, 0.f};

    #pragma unroll
    for (int kk = 0; kk < 4; ++kk) {
        int abyte = (arow * 256 + kk * 64 + lgrp * 16) ^ ((arow & 7) << 4);
        bf16x8 afrag = *(bf16x8*)((char*)a_lds + abyte);
        #pragma unroll
        for (int nf = 0; nf < 8; ++nf) {
            int bcol = nf * 16 + lrow;
            int bbyte = (bcol * 256 + kk * 64 + lgrp * 16) ^ ((bcol & 7) << 4);
            bf16x8 bfrag = *(bf16x8*)((char*)w_lds + bbyte);
            acc[nf] = __builtin_amdgcn_mfma_f32_16x16x32_bf16(afrag, bfrag, acc[nf], 0, 0, 0);
        }
    }

    #pragma unroll
    for (int nf = 0; nf < 8; ++nf) {
        #pragma unroll
        for (int r = 0; r < 4; ++r) {
            int grow = m0 + wv * 16 + lgrp * 4 + r;
            if (grow < n) {
                int col = nf * 16 + lrow;
                out[(size_t)grow * D + col] = f2bf(acc[nf][r]);
            }
        }
    }
}

// ---------------- fused aggregate + bias + (leaky) + residual + LayerNorm ----------------
// Wave-per-node, bf16 gather table, 8 gathers in flight, scalar edge-pair loads.
// MODE 0: out = LN1(leaky(agg + b1) + x)
// MODE 1: out = leaky(LN2(agg + b2 + x))
template <int MODE>
__global__ __launch_bounds__(256) void agg_ln(const unsigned* __restrict__ h,  // bf16x2 per dword
                                              const float* __restrict__ x,
                                              const float* __restrict__ bias,
                                              const float* __restrict__ gamma,
                                              const float* __restrict__ beta,
                                              const float* __restrict__ dinv,
                                              const int* __restrict__ rowstart,
                                              const int2* __restrict__ csr_pair,
                                              float* __restrict__ out) {
    int wid = threadIdx.x >> 6;
    int lane = threadIdx.x & 63;
    int i = blockIdx.x * 4 + wid;   // NN = 50000 = 12500 * 4, exact
    float di = dinv[i];
    size_t rowoff = (size_t)i * D + 2 * lane;

    float hx, hy;
    bf2x(h[(size_t)i * (D / 2) + lane], hx, hy);
    float accx = di * di * hx, accy = di * di * hy;

    // wave-uniform bounds -> scalar loads for the pair stream
    int e = __builtin_amdgcn_readfirstlane(rowstart[i]);
    int e1 = __builtin_amdgcn_readfirstlane(rowstart[i + 1]);

    for (; e + 8 <= e1; e += 8) {
        int4 q0 = *(const int4*)&csr_pair[e + 0];  // pairs e,e+1
        int4 q1 = *(const int4*)&csr_pair[e + 2];
        int4 q2 = *(const int4*)&csr_pair[e + 4];
        int4 q3 = *(const int4*)&csr_pair[e + 6];
        unsigned g0 = h[(size_t)q0.x * (D / 2) + lane];
        unsigned g1 = h[(size_t)q0.z * (D / 2) + lane];
        unsigned g2 = h[(size_t)q1.x * (D / 2) + lane];
        unsigned g3 = h[(size_t)q1.z * (D / 2) + lane];
        unsigned g4 = h[(size_t)q2.x * (D / 2) + lane];
        unsigned g5 = h[(size_t)q2.z * (D / 2) + lane];
        unsigned g6 = h[(size_t)q3.x * (D / 2) + lane];
        unsigned g7 = h[(size_t)q3.z * (D / 2) + lane];
        float ax, ay, c;
        c = __int_as_float(q0.y); bf2x(g0, ax, ay); accx = fmaf(c, ax, accx); accy = fmaf(c, ay, accy);
        c = __int_as_float(q0.w); bf2x(g1, ax, ay); accx = fmaf(c, ax, accx); accy = fmaf(c, ay, accy);
        c = __int_as_float(q1.y); bf2x(g2, ax, ay); accx = fmaf(c, ax, accx); accy = fmaf(c, ay, accy);
        c = __int_as_float(q1.w); bf2x(g3, ax, ay); accx = fmaf(c, ax, accx); accy = fmaf(c, ay, accy);
        c = __int_as_float(q2.y); bf2x(g4, ax, ay); accx = fmaf(c, ax, accx); accy = fmaf(c, ay, accy);
        c = __int_as_float(q2.w); bf2x(g5, ax, ay); accx = fmaf(c, ax, accx); accy = fmaf(c, ay, accy);
        c = __int_as_float(q3.y); bf2x(g6, ax, ay); accx = fmaf(c, ax, accx); accy = fmaf(c, ay, accy);
        c = __int_as_float(q3.w); bf2x(g7, ax, ay); accx = fmaf(c, ax, accx); accy = fmaf(c, ay, accy);
    }
    for (; e < e1; ++e) {
        int2 p = csr_pair[e];
        unsigned g = h[(size_t)p.x * (D / 2) + lane];
        float c = __int_as_float(p.y);
        float ax, ay;
        bf2x(g, ax, ay);
        accx = fmaf(c, ax, accx); accy = fmaf(c, ay, accy);
    }

    float2 bv = *(const float2*)&bias[2 * lane];
    accx += bv.x; accy += bv.y;
    if (MODE == 0) {
        accx = accx > 0.f ? accx : NEG_SLOPE * accx;
        accy = accy > 0.f ? accy : NEG_SLOPE * accy;
    }
    float2 xv = *(const float2*)&x[rowoff];
    float v0 = accx + xv.x, v1 = accy + xv.y;

    float s1 = v0 + v1, s2 = v0 * v0 + v1 * v1;
    #pragma unroll
    for (int off = 1; off < 64; off <<= 1) {
        s1 += __shfl_xor(s1, off, 64);
        s2 += __shfl_xor(s2, off, 64);
    }
    float mu = s1 * (1.f / 128.f);
    float var = fmaxf(s2 * (1.f / 128.f) - mu * mu, 0.f);
    float rs = rsqrtf(var + LN_EPS);

    float2 gv = *(const float2*)&gamma[2 * lane];
    float2 bt = *(const float2*)&beta[2 * lane];
    float o0 = (v0 - mu) * rs * gv.x + bt.x;
    float o1 = (v1 - mu) * rs * gv.y + bt.y;
    if (MODE == 1) {
        o0 = o0 > 0.f ? o0 : NEG_SLOPE * o0;
        o1 = o1 > 0.f ? o1 : NEG_SLOPE * o1;
    }
    *(float2*)&out[rowoff] = make_float2(o0, o1);
}

extern "C" void kernel_launch(void* const* d_in, const int* in_sizes, int n_in,
                              void* d_out, int out_size, void* d_ws, size_t ws_size,
                              hipStream_t stream) {
    const float* x    = (const float*)d_in[0];
    const int*   ei   = (const int*)d_in[1];   // [2, NE]: row0 src, row1 dst
    const float* W1   = (const float*)d_in[2];
    const float* b1   = (const float*)d_in[3];
    const float* ln1g = (const float*)d_in[4];
    const float* ln1b = (const float*)d_in[5];
    const float* W2   = (const float*)d_in[6];
    const float* b2   = (const float*)d_in[7];
    const float* ln2g = (const float*)d_in[8];
    const float* ln2b = (const float*)d_in[9];
    float* out = (float*)d_out;

    const int* srcp = ei;
    const int* dstp = ei + NE;

    char* ws = (char*)d_ws;
    size_t p = 0;
    auto alloc = [&](size_t bytes) {
        char* r = ws + p;
        p += (bytes + 255) & ~(size_t)255;
        return r;
    };
    int*   deg      = (int*)alloc(NN * 4);
    int*   rowtmp   = (int*)alloc(NN * 4);
    int*   rowstart = (int*)alloc((NN + 1) * 4);
    int*   cursor   = (int*)alloc(NN * 4);
    int*   blocksum = (int*)alloc(256 * 4);
    int*   blockoff = (int*)alloc(256 * 4);
    int*   dummy    = (int*)alloc(256 * 4);
    float* dinv     = (float*)alloc(NN * 4);
    int2*  csr_pair = (int2*)alloc((size_t)NE * 8);
    unsigned short* hbf = (unsigned short*)alloc((size_t)NN * D * 2);  // bf16 gather table
    unsigned short* wt1 = (unsigned short*)alloc(D * D * 2);
    unsigned short* wt2 = (unsigned short*)alloc(D * D * 2);

    hipMemsetAsync(deg, 0, NN * 4, stream);
    hipMemsetAsync(cursor, 0, NN * 4, stream);

    deg_kernel<<<(NE + 255) / 256, 256, 0, stream>>>(dstp, deg, NE);
    dinv_kernel<<<(NN + 255) / 256, 256, 0, stream>>>(deg, dinv, NN);

    int nblk = (NN + 255) / 256;  // 196
    scan_block<<<nblk, 256, 0, stream>>>(deg, rowtmp, blocksum, NN);
    scan_block<<<1, 256, 0, stream>>>(blocksum, blockoff, dummy, nblk);
    scan_combine<<<nblk, 256, 0, stream>>>(rowtmp, blockoff, rowstart, NN, NE);

    scatter_kernel<<<(NE + 255) / 256, 256, 0, stream>>>(srcp, dstp, dinv, rowstart,
                                                         cursor, csr_pair, NE);

    wt_pack<<<D * D / 256, 256, 0, stream>>>(W1, wt1);
    wt_pack<<<D * D / 256, 256, 0, stream>>>(W2, wt2);

    // Layer 1: h1 = bf16(x @ W1) ; out = LN1(leaky(agg(h1)+b1) + x)
    gemm_mfma<<<(NN + 63) / 64, 256, 0, stream>>>(x, wt1, hbf, NN);
    agg_ln<0><<<NN / 4, 256, 0, stream>>>((const unsigned*)hbf, x, b1, ln1g, ln1b, dinv,
                                          rowstart, csr_pair, out);

    // Layer 2: t = bf16(out @ W2) ; out = leaky(LN2(agg(t)+b2 + x))
    gemm_mfma<<<(NN + 63) / 64, 256, 0, stream>>>(out, wt2, hbf, NN);
    agg_ln<1><<<NN / 4, 256, 0, stream>>>((const unsigned*)hbf, x, b2, ln2g, ln2b, dinv,
                                          rowstart, csr_pair, out);
}

// Round 5
// 172.068 us; speedup vs baseline: 2.0571x; 1.1526x over previous
//
#include <hip/hip_runtime.h>
#include <hip/hip_bf16.h>

#define NN 50000
#define NE 800000
#define D 128
#define NEG_SLOPE 0.01f
#define LN_EPS 1e-5f

#define NPB 256                 // nodes per bucket (bucket = dst >> 8)
#define NB 196                  // ceil(NN / NPB)
#define ECH 8192                // edges per workgroup in bucket pass
#define NCH ((NE + ECH - 1) / ECH)  // 98

typedef __attribute__((ext_vector_type(8))) short bf16x8;
typedef __attribute__((ext_vector_type(4))) float f32x4;

// f32 -> bf16 round-to-nearest-even (finite values)
__device__ inline unsigned short f2bf(float f) {
    unsigned u = __float_as_uint(f);
    unsigned r = 0x7FFFu + ((u >> 16) & 1u);
    return (unsigned short)((u + r) >> 16);
}
// unpack one dword = 2 bf16 -> 2 floats
__device__ inline void bf2x(unsigned u, float& lo, float& hi) {
    lo = __uint_as_float(u << 16);
    hi = __uint_as_float(u & 0xFFFF0000u);
}

// ---------------- bucket-sorted CSR build (no random global scatter) ----------------

__global__ __launch_bounds__(256) void bucket_count(const int* __restrict__ dst,
                                                    int* __restrict__ bcount, int ne) {
    __shared__ int h[NB];
    int t = threadIdx.x;
    if (t < NB) h[t] = 0;
    __syncthreads();
    int e0 = blockIdx.x * ECH;
    int ecnt = min(ECH, ne - e0);
    for (int k = t; k < ecnt; k += 256) atomicAdd(&h[dst[e0 + k] >> 8], 1);
    __syncthreads();
    if (t < NB && h[t]) atomicAdd(&bcount[t], h[t]);
}

__global__ void bucket_scan(const int* __restrict__ bcount, int* __restrict__ bstart) {
    __shared__ int tmp[256];
    int t = threadIdx.x;
    int v = (t < NB) ? bcount[t] : 0;
    tmp[t] = v;
    __syncthreads();
    for (int off = 1; off < 256; off <<= 1) {
        int u = (t >= off) ? tmp[t - off] : 0;
        __syncthreads();
        tmp[t] += u;
        __syncthreads();
    }
    if (t < NB) bstart[t] = tmp[t] - v;
    if (t == 0) bstart[NB] = NE;
}

// LDS-binned scatter of (src,dst) into bucket-grouped bedge. Each wg flushes
// contiguous per-bucket runs -> full-cacheline global writes.
__global__ __launch_bounds__(256) void bucket_scatter(const int* __restrict__ src,
                                                      const int* __restrict__ dst,
                                                      const int* __restrict__ bstart,
                                                      int* __restrict__ bcursor,
                                                      int2* __restrict__ bedge, int ne) {
    __shared__ int2 stage[ECH];                      // 64 KB
    __shared__ int hist[NB], lofs[NB], lcur[NB], gbase[NB];
    __shared__ int tmp[256];
    int t = threadIdx.x;
    int e0 = blockIdx.x * ECH;
    int ecnt = min(ECH, ne - e0);
    if (t < NB) hist[t] = 0;
    __syncthreads();
    for (int k = t; k < ecnt; k += 256) atomicAdd(&hist[dst[e0 + k] >> 8], 1);
    __syncthreads();
    int v = (t < NB) ? hist[t] : 0;
    tmp[t] = v;
    __syncthreads();
    for (int off = 1; off < 256; off <<= 1) {
        int u = (t >= off) ? tmp[t - off] : 0;
        __syncthreads();
        tmp[t] += u;
        __syncthreads();
    }
    if (t < NB) {
        lofs[t] = tmp[t] - v;
        lcur[t] = tmp[t] - v;
        gbase[t] = atomicAdd(&bcursor[t], v);        // reserve global run
    }
    __syncthreads();
    for (int k = t; k < ecnt; k += 256) {
        int s = src[e0 + k], d = dst[e0 + k];
        int p = atomicAdd(&lcur[d >> 8], 1);
        stage[p] = make_int2(s, d);
    }
    __syncthreads();
    for (int k = t; k < ecnt; k += 256) {
        int2 eg = stage[k];
        int b = eg.y >> 8;
        bedge[bstart[b] + gbase[b] + (k - lofs[b])] = eg;
    }
}

// Per-bucket node histogram -> deg + dinv (sequential writes, no global atomics).
__global__ __launch_bounds__(256) void deg_dinv(const int2* __restrict__ bedge,
                                                const int* __restrict__ bstart,
                                                int* __restrict__ deg,
                                                float* __restrict__ dinv) {
    __shared__ int h[NPB];
    int b = blockIdx.x, t = threadIdx.x;
    h[t] = 0;
    __syncthreads();
    int s0 = bstart[b], s1 = bstart[b + 1];
    for (int k = s0 + t; k < s1; k += 256) atomicAdd(&h[bedge[k].y & 255], 1);
    __syncthreads();
    int node = b * NPB + t;
    if (node < NN) {
        deg[node] = h[t];
        dinv[node] = rsqrtf((float)(h[t] + 1));      // +1: self-loop
    }
}

__global__ void scan_block(const int* __restrict__ in, int* __restrict__ out_excl,
                           int* __restrict__ blocksum, int n) {
    __shared__ int tmp[256];
    int t = threadIdx.x, b = blockIdx.x, i = b * 256 + t;
    int v = (i < n) ? in[i] : 0;
    tmp[t] = v;
    __syncthreads();
    for (int off = 1; off < 256; off <<= 1) {
        int u = (t >= off) ? tmp[t - off] : 0;
        __syncthreads();
        tmp[t] += u;
        __syncthreads();
    }
    if (i < n) out_excl[i] = tmp[t] - v;
    if (t == 255) blocksum[b] = tmp[255];
}

__global__ void scan_combine(const int* __restrict__ rowtmp, const int* __restrict__ blockoff,
                             int* __restrict__ rowstart, int n, int ne) {
    int i = blockIdx.x * 256 + threadIdx.x;
    if (i < n) rowstart[i] = rowtmp[i] + blockoff[i >> 8];
    if (i == 0) rowstart[n] = ne;
}

// Per-bucket scatter into final CSR. Each wg owns an exclusive ~33 KB csr region
// (L2-resident, full lines written once); cursors live in LDS.
__global__ __launch_bounds__(256) void csr_scatter(const int2* __restrict__ bedge,
                                                   const int* __restrict__ bstart,
                                                   const int* __restrict__ rowstart,
                                                   const float* __restrict__ dinv,
                                                   int2* __restrict__ csr_pair) {
    __shared__ int cur[NPB];
    int b = blockIdx.x, t = threadIdx.x;
    cur[t] = 0;
    __syncthreads();
    int s0 = bstart[b], s1 = bstart[b + 1];
    for (int k = s0 + t; k < s1; k += 256) {
        int2 eg = bedge[k];
        int p = atomicAdd(&cur[eg.y & 255], 1);
        float coef = dinv[eg.x] * dinv[eg.y];
        csr_pair[rowstart[eg.y] + p] = make_int2(eg.x, __float_as_int(coef));
    }
}

// W [128][128] f32 (W[k][n]) -> WT [128][128] bf16 (WT[n][k])
__global__ void wt_pack(const float* __restrict__ W, unsigned short* __restrict__ WT) {
    int tid = blockIdx.x * 256 + threadIdx.x;
    int nn = tid & 127, k = tid >> 7;
    WT[nn * 128 + k] = f2bf(W[k * 128 + nn]);
}

// ---------------- MFMA GEMM: out_bf16[n x 128] = bf16(A[n x 128]) @ WT^T ----------------
__global__ __launch_bounds__(256) void gemm_mfma(const float* __restrict__ A,
                                                 const unsigned short* __restrict__ WT,
                                                 unsigned short* __restrict__ out, int n) {
    __shared__ __align__(16) unsigned short a_lds[64 * 128];   // 16 KB
    __shared__ __align__(16) unsigned short w_lds[128 * 128];  // 32 KB
    int t = threadIdx.x;
    int m0 = blockIdx.x * 64;

    #pragma unroll
    for (int it = 0; it < 8; ++it) {
        int idx = it * 256 + t;
        int row = idx >> 4, c = idx & 15;
        uint4 v = *(const uint4*)&WT[row * 128 + c * 8];
        int byte = (row * 256 + c * 16) ^ ((row & 7) << 4);
        *(uint4*)((char*)w_lds + byte) = v;
    }
    #pragma unroll
    for (int it = 0; it < 4; ++it) {
        int idx = it * 256 + t;
        int row = idx >> 4, c = idx & 15;
        int grow = m0 + row;
        float4 v0 = make_float4(0.f, 0.f, 0.f, 0.f), v1 = v0;
        if (grow < n) {
            v0 = *(const float4*)&A[(size_t)grow * D + c * 8];
            v1 = *(const float4*)&A[(size_t)grow * D + c * 8 + 4];
        }
        uint2 lo, hi;
        lo.x = (unsigned)f2bf(v0.x) | ((unsigned)f2bf(v0.y) << 16);
        lo.y = (unsigned)f2bf(v0.z) | ((unsigned)f2bf(v0.w) << 16);
        hi.x = (unsigned)f2bf(v1.x) | ((unsigned)f2bf(v1.y) << 16);
        hi.y = (unsigned)f2bf(v1.z) | ((unsigned)f2bf(v1.w) << 16);
        int byte = (row * 256 + c * 16) ^ ((row & 7) << 4);
        *(uint4*)((char*)a_lds + byte) = make_uint4(lo.x, lo.y, hi.x, hi.y);
    }
    __syncthreads();

    int wv = t >> 6, l = t & 63;
    int lrow = l & 15, lgrp = l >> 4;
    int arow = wv * 16 + lrow;

    f32x4 acc[8];
    #pragma unroll
    for (int nf = 0; nf < 8; ++nf) acc[nf] = (f32x4){0.f, 0.f, 0.f, 0.f};

    #pragma unroll
    for (int kk = 0; kk < 4; ++kk) {
        int abyte = (arow * 256 + kk * 64 + lgrp * 16) ^ ((arow & 7) << 4);
        bf16x8 afrag = *(bf16x8*)((char*)a_lds + abyte);
        #pragma unroll
        for (int nf = 0; nf < 8; ++nf) {
            int bcol = nf * 16 + lrow;
            int bbyte = (bcol * 256 + kk * 64 + lgrp * 16) ^ ((bcol & 7) << 4);
            bf16x8 bfrag = *(bf16x8*)((char*)w_lds + bbyte);
            acc[nf] = __builtin_amdgcn_mfma_f32_16x16x32_bf16(afrag, bfrag, acc[nf], 0, 0, 0);
        }
    }

    #pragma unroll
    for (int nf = 0; nf < 8; ++nf) {
        #pragma unroll
        for (int r = 0; r < 4; ++r) {
            int grow = m0 + wv * 16 + lgrp * 4 + r;
            if (grow < n) {
                int col = nf * 16 + lrow;
                out[(size_t)grow * D + col] = f2bf(acc[nf][r]);
            }
        }
    }
}

// ---------------- fused aggregate + bias + (leaky) + residual + LayerNorm ----------------
template <int MODE>
__global__ __launch_bounds__(256) void agg_ln(const unsigned* __restrict__ h,  // bf16x2 per dword
                                              const float* __restrict__ x,
                                              const float* __restrict__ bias,
                                              const float* __restrict__ gamma,
                                              const float* __restrict__ beta,
                                              const float* __restrict__ dinv,
                                              const int* __restrict__ rowstart,
                                              const int2* __restrict__ csr_pair,
                                              float* __restrict__ out) {
    int wid = threadIdx.x >> 6;
    int lane = threadIdx.x & 63;
    int i = blockIdx.x * 4 + wid;   // NN = 50000 = 12500 * 4, exact
    float di = dinv[i];
    size_t rowoff = (size_t)i * D + 2 * lane;

    float hx, hy;
    bf2x(h[(size_t)i * (D / 2) + lane], hx, hy);
    float accx = di * di * hx, accy = di * di * hy;

    int e = __builtin_amdgcn_readfirstlane(rowstart[i]);
    int e1 = __builtin_amdgcn_readfirstlane(rowstart[i + 1]);

    for (; e + 8 <= e1; e += 8) {
        int4 q0 = *(const int4*)&csr_pair[e + 0];
        int4 q1 = *(const int4*)&csr_pair[e + 2];
        int4 q2 = *(const int4*)&csr_pair[e + 4];
        int4 q3 = *(const int4*)&csr_pair[e + 6];
        unsigned g0 = h[(size_t)q0.x * (D / 2) + lane];
        unsigned g1 = h[(size_t)q0.z * (D / 2) + lane];
        unsigned g2 = h[(size_t)q1.x * (D / 2) + lane];
        unsigned g3 = h[(size_t)q1.z * (D / 2) + lane];
        unsigned g4 = h[(size_t)q2.x * (D / 2) + lane];
        unsigned g5 = h[(size_t)q2.z * (D / 2) + lane];
        unsigned g6 = h[(size_t)q3.x * (D / 2) + lane];
        unsigned g7 = h[(size_t)q3.z * (D / 2) + lane];
        float ax, ay, c;
        c = __int_as_float(q0.y); bf2x(g0, ax, ay); accx = fmaf(c, ax, accx); accy = fmaf(c, ay, accy);
        c = __int_as_float(q0.w); bf2x(g1, ax, ay); accx = fmaf(c, ax, accx); accy = fmaf(c, ay, accy);
        c = __int_as_float(q1.y); bf2x(g2, ax, ay); accx = fmaf(c, ax, accx); accy = fmaf(c, ay, accy);
        c = __int_as_float(q1.w); bf2x(g3, ax, ay); accx = fmaf(c, ax, accx); accy = fmaf(c, ay, accy);
        c = __int_as_float(q2.y); bf2x(g4, ax, ay); accx = fmaf(c, ax, accx); accy = fmaf(c, ay, accy);
        c = __int_as_float(q2.w); bf2x(g5, ax, ay); accx = fmaf(c, ax, accx); accy = fmaf(c, ay, accy);
        c = __int_as_float(q3.y); bf2x(g6, ax, ay); accx = fmaf(c, ax, accx); accy = fmaf(c, ay, accy);
        c = __int_as_float(q3.w); bf2x(g7, ax, ay); accx = fmaf(c, ax, accx); accy = fmaf(c, ay, accy);
    }
    for (; e < e1; ++e) {
        int2 p = csr_pair[e];
        unsigned g = h[(size_t)p.x * (D / 2) + lane];
        float c = __int_as_float(p.y);
        float ax, ay;
        bf2x(g, ax, ay);
        accx = fmaf(c, ax, accx); accy = fmaf(c, ay, accy);
    }

    float2 bv = *(const float2*)&bias[2 * lane];
    accx += bv.x; accy += bv.y;
    if (MODE == 0) {
        accx = accx > 0.f ? accx : NEG_SLOPE * accx;
        accy = accy > 0.f ? accy : NEG_SLOPE * accy;
    }
    float2 xv = *(const float2*)&x[rowoff];
    float v0 = accx + xv.x, v1 = accy + xv.y;

    float s1 = v0 + v1, s2 = v0 * v0 + v1 * v1;
    #pragma unroll
    for (int off = 1; off < 64; off <<= 1) {
        s1 += __shfl_xor(s1, off, 64);
        s2 += __shfl_xor(s2, off, 64);
    }
    float mu = s1 * (1.f / 128.f);
    float var = fmaxf(s2 * (1.f / 128.f) - mu * mu, 0.f);
    float rs = rsqrtf(var + LN_EPS);

    float2 gv = *(const float2*)&gamma[2 * lane];
    float2 bt = *(const float2*)&beta[2 * lane];
    float o0 = (v0 - mu) * rs * gv.x + bt.x;
    float o1 = (v1 - mu) * rs * gv.y + bt.y;
    if (MODE == 1) {
        o0 = o0 > 0.f ? o0 : NEG_SLOPE * o0;
        o1 = o1 > 0.f ? o1 : NEG_SLOPE * o1;
    }
    *(float2*)&out[rowoff] = make_float2(o0, o1);
}

extern "C" void kernel_launch(void* const* d_in, const int* in_sizes, int n_in,
                              void* d_out, int out_size, void* d_ws, size_t ws_size,
                              hipStream_t stream) {
    const float* x    = (const float*)d_in[0];
    const int*   ei   = (const int*)d_in[1];   // [2, NE]: row0 src, row1 dst
    const float* W1   = (const float*)d_in[2];
    const float* b1   = (const float*)d_in[3];
    const float* ln1g = (const float*)d_in[4];
    const float* ln1b = (const float*)d_in[5];
    const float* W2   = (const float*)d_in[6];
    const float* b2   = (const float*)d_in[7];
    const float* ln2g = (const float*)d_in[8];
    const float* ln2b = (const float*)d_in[9];
    float* out = (float*)d_out;

    const int* srcp = ei;
    const int* dstp = ei + NE;

    char* ws = (char*)d_ws;
    size_t p = 0;
    auto alloc = [&](size_t bytes) {
        char* r = ws + p;
        p += (bytes + 255) & ~(size_t)255;
        return r;
    };
    int*   deg      = (int*)alloc(NN * 4);
    int*   rowtmp   = (int*)alloc(NN * 4);
    int*   rowstart = (int*)alloc((NN + 1) * 4);
    int*   blocksum = (int*)alloc(256 * 4);
    int*   blockoff = (int*)alloc(256 * 4);
    int*   dummy    = (int*)alloc(256 * 4);
    float* dinv     = (float*)alloc(NN * 4);
    int*   bcount   = (int*)alloc(NB * 4);
    int*   bstart   = (int*)alloc((NB + 1) * 4);
    int*   bcursor  = (int*)alloc(NB * 4);
    int2*  bedge    = (int2*)alloc((size_t)NE * 8);
    int2*  csr_pair = (int2*)alloc((size_t)NE * 8);
    unsigned short* hbf = (unsigned short*)alloc((size_t)NN * D * 2);  // bf16 gather table
    unsigned short* wt1 = (unsigned short*)alloc(D * D * 2);
    unsigned short* wt2 = (unsigned short*)alloc(D * D * 2);

    hipMemsetAsync(bcount, 0, NB * 4, stream);
    hipMemsetAsync(bcursor, 0, NB * 4, stream);

    bucket_count<<<NCH, 256, 0, stream>>>(dstp, bcount, NE);
    bucket_scan<<<1, 256, 0, stream>>>(bcount, bstart);
    bucket_scatter<<<NCH, 256, 0, stream>>>(srcp, dstp, bstart, bcursor, bedge, NE);
    deg_dinv<<<NB, 256, 0, stream>>>(bedge, bstart, deg, dinv);

    int nblk = (NN + 255) / 256;  // 196
    scan_block<<<nblk, 256, 0, stream>>>(deg, rowtmp, blocksum, NN);
    scan_block<<<1, 256, 0, stream>>>(blocksum, blockoff, dummy, nblk);
    scan_combine<<<nblk, 256, 0, stream>>>(rowtmp, blockoff, rowstart, NN, NE);

    csr_scatter<<<NB, 256, 0, stream>>>(bedge, bstart, rowstart, dinv, csr_pair);

    wt_pack<<<D * D / 256, 256, 0, stream>>>(W1, wt1);
    wt_pack<<<D * D / 256, 256, 0, stream>>>(W2, wt2);

    // Layer 1: h1 = bf16(x @ W1) ; out = LN1(leaky(agg(h1)+b1) + x)
    gemm_mfma<<<(NN + 63) / 64, 256, 0, stream>>>(x, wt1, hbf, NN);
    agg_ln<0><<<NN / 4, 256, 0, stream>>>((const unsigned*)hbf, x, b1, ln1g, ln1b, dinv,
                                          rowstart, csr_pair, out);

    // Layer 2: t = bf16(out @ W2) ; out = leaky(LN2(agg(t)+b2 + x))
    gemm_mfma<<<(NN + 63) / 64, 256, 0, stream>>>(out, W2 ? wt2 : wt2, hbf, NN);
    agg_ln<1><<<NN / 4, 256, 0, stream>>>((const unsigned*)hbf, x, b2, ln2g, ln2b, dinv,
                                          rowstart, csr_pair, out);
}

// Round 6
// 164.137 us; speedup vs baseline: 2.1565x; 1.0483x over previous
//
#include <hip/hip_runtime.h>
#include <hip/hip_bf16.h>

#define NN 50000
#define NE 800000
#define D 128
#define NEG_SLOPE 0.01f
#define LN_EPS 1e-5f

#define NPB 256                 // nodes per bucket (bucket = dst >> 8)
#define NB 196                  // ceil(NN / NPB); NB*256 = 50176
#define ECH 8192                // edges per workgroup in bucket pass
#define NCH ((NE + ECH - 1) / ECH)  // 98

typedef __attribute__((ext_vector_type(8))) short bf16x8;
typedef __attribute__((ext_vector_type(4))) float f32x4;

// f32 -> bf16 round-to-nearest-even (finite values)
__device__ inline unsigned short f2bf(float f) {
    unsigned u = __float_as_uint(f);
    unsigned r = 0x7FFFu + ((u >> 16) & 1u);
    return (unsigned short)((u + r) >> 16);
}
// unpack one dword = 2 bf16 -> 2 floats
__device__ inline void bf2x(unsigned u, float& lo, float& hi) {
    lo = __uint_as_float(u << 16);
    hi = __uint_as_float(u & 0xFFFF0000u);
}

// ---------------- bucket-sorted CSR build (no random global scatter) ----------------

__global__ __launch_bounds__(256) void bucket_count(const int* __restrict__ dst,
                                                    int* __restrict__ bcount, int ne) {
    __shared__ int h[NB];
    int t = threadIdx.x;
    if (t < NB) h[t] = 0;
    __syncthreads();
    int e0 = blockIdx.x * ECH;
    int ecnt = min(ECH, ne - e0);
    for (int k = t; k < ecnt; k += 256) atomicAdd(&h[dst[e0 + k] >> 8], 1);
    __syncthreads();
    if (t < NB && h[t]) atomicAdd(&bcount[t], h[t]);
}

__global__ void bucket_scan(const int* __restrict__ bcount, int* __restrict__ bstart) {
    __shared__ int tmp[256];
    int t = threadIdx.x;
    int v = (t < NB) ? bcount[t] : 0;
    tmp[t] = v;
    __syncthreads();
    for (int off = 1; off < 256; off <<= 1) {
        int u = (t >= off) ? tmp[t - off] : 0;
        __syncthreads();
        tmp[t] += u;
        __syncthreads();
    }
    if (t < NB) bstart[t] = tmp[t] - v;
    if (t == 0) bstart[NB] = NE;
}

// LDS-binned scatter of (src,dst) into bucket-grouped bedge: full-line global writes.
__global__ __launch_bounds__(256) void bucket_scatter(const int* __restrict__ src,
                                                      const int* __restrict__ dst,
                                                      const int* __restrict__ bstart,
                                                      int* __restrict__ bcursor,
                                                      int2* __restrict__ bedge, int ne) {
    __shared__ int2 stage[ECH];                      // 64 KB
    __shared__ int hist[NB], lofs[NB], lcur[NB], gbase[NB];
    __shared__ int tmp[256];
    int t = threadIdx.x;
    int e0 = blockIdx.x * ECH;
    int ecnt = min(ECH, ne - e0);
    if (t < NB) hist[t] = 0;
    __syncthreads();
    for (int k = t; k < ecnt; k += 256) atomicAdd(&hist[dst[e0 + k] >> 8], 1);
    __syncthreads();
    int v = (t < NB) ? hist[t] : 0;
    tmp[t] = v;
    __syncthreads();
    for (int off = 1; off < 256; off <<= 1) {
        int u = (t >= off) ? tmp[t - off] : 0;
        __syncthreads();
        tmp[t] += u;
        __syncthreads();
    }
    if (t < NB) {
        lofs[t] = tmp[t] - v;
        lcur[t] = tmp[t] - v;
        gbase[t] = atomicAdd(&bcursor[t], v);        // reserve global run
    }
    __syncthreads();
    for (int k = t; k < ecnt; k += 256) {
        int s = src[e0 + k], d = dst[e0 + k];
        int p = atomicAdd(&lcur[d >> 8], 1);
        stage[p] = make_int2(s, d);
    }
    __syncthreads();
    for (int k = t; k < ecnt; k += 256) {
        int2 eg = stage[k];
        int b = eg.y >> 8;
        bedge[bstart[b] + gbase[b] + (k - lofs[b])] = eg;
    }
}

// Per-bucket node histogram -> dinv + local exclusive scan of PADDED degrees
// (padded to multiple of 8) + per-bucket padded total.
__global__ __launch_bounds__(256) void node_count(const int2* __restrict__ bedge,
                                                  const int* __restrict__ bstart,
                                                  float* __restrict__ dinv,
                                                  int* __restrict__ prowtmp,
                                                  int* __restrict__ pbsum) {
    __shared__ int h[NPB];
    __shared__ int tmp[256];
    int b = blockIdx.x, t = threadIdx.x;
    h[t] = 0;
    __syncthreads();
    int s0 = bstart[b], s1 = bstart[b + 1];
    for (int k = s0 + t; k < s1; k += 256) atomicAdd(&h[bedge[k].y & 255], 1);
    __syncthreads();
    int deg = h[t];
    int node = b * NPB + t;
    if (node < NN) dinv[node] = rsqrtf((float)(deg + 1));   // +1: self-loop
    int pdeg = (deg + 7) & ~7;                              // pad to multiple of 8
    tmp[t] = pdeg;
    __syncthreads();
    for (int off = 1; off < 256; off <<= 1) {
        int u = (t >= off) ? tmp[t - off] : 0;
        __syncthreads();
        tmp[t] += u;
        __syncthreads();
    }
    prowtmp[b * NPB + t] = tmp[t] - pdeg;
    if (t == 255) pbsum[b] = tmp[255];
}

// Scan padded bucket totals; writes rowstart[NN] = padded grand total.
__global__ void pbucket_scan(const int* __restrict__ pbsum, int* __restrict__ pbstart,
                             int* __restrict__ rowstart_nn) {
    __shared__ int tmp[256];
    int t = threadIdx.x;
    int v = (t < NB) ? pbsum[t] : 0;
    tmp[t] = v;
    __syncthreads();
    for (int off = 1; off < 256; off <<= 1) {
        int u = (t >= off) ? tmp[t - off] : 0;
        __syncthreads();
        tmp[t] += u;
        __syncthreads();
    }
    if (t < NB) pbstart[t] = tmp[t] - v;
    if (t == 255) *rowstart_nn = tmp[255];
}

// Per-bucket scatter into padded CSR; writes rowstart and pads each node's run
// to a multiple of 8 with (self, coef=0) dummy edges (cache-hot, zero effect).
__global__ __launch_bounds__(256) void csr_scatter(const int2* __restrict__ bedge,
                                                   const int* __restrict__ bstart,
                                                   const int* __restrict__ pbstart,
                                                   const int* __restrict__ prowtmp,
                                                   const float* __restrict__ dinv,
                                                   int* __restrict__ rowstart,
                                                   int2* __restrict__ csr_pair) {
    __shared__ int cur[NPB];
    __shared__ int rl[NPB];
    int b = blockIdx.x, t = threadIdx.x;
    int base = pbstart[b];
    int node = b * NPB + t;
    int r = base + prowtmp[node];
    rl[t] = r;
    cur[t] = 0;
    if (node < NN) rowstart[node] = r;
    __syncthreads();
    int s0 = bstart[b], s1 = bstart[b + 1];
    for (int k = s0 + t; k < s1; k += 256) {
        int2 eg = bedge[k];
        int li = eg.y & 255;
        int p = atomicAdd(&cur[li], 1);
        float coef = dinv[eg.x] * dinv[eg.y];
        csr_pair[rl[li] + p] = make_int2(eg.x, __float_as_int(coef));
    }
    __syncthreads();
    int deg = cur[t];
    int pend = (deg + 7) & ~7;
    int selfsrc = (node < NN) ? node : 0;
    for (int k = deg; k < pend; ++k)
        csr_pair[rl[t] + k] = make_int2(selfsrc, 0);
}

// Pack W1 and W2 (f32 [k][n]) -> bf16 [n][k] in ONE launch.
__global__ void wt_pack2(const float* __restrict__ W1, const float* __restrict__ W2,
                         unsigned short* __restrict__ WT1, unsigned short* __restrict__ WT2) {
    int tid = blockIdx.x * 256 + threadIdx.x;      // 2 * 16384 threads
    const float* W = (tid < D * D) ? W1 : W2;
    unsigned short* WT = (tid < D * D) ? WT1 : WT2;
    int id = tid & (D * D - 1);
    int nn = id & 127, k = id >> 7;
    WT[nn * 128 + k] = f2bf(W[k * 128 + nn]);
}

// ---------------- MFMA GEMM: out_bf16[n x 128] = bf16(A[n x 128]) @ WT^T ----------------
__global__ __launch_bounds__(256) void gemm_mfma(const float* __restrict__ A,
                                                 const unsigned short* __restrict__ WT,
                                                 unsigned short* __restrict__ out, int n) {
    __shared__ __align__(16) unsigned short a_lds[64 * 128];   // 16 KB
    __shared__ __align__(16) unsigned short w_lds[128 * 128];  // 32 KB
    int t = threadIdx.x;
    int m0 = blockIdx.x * 64;

    #pragma unroll
    for (int it = 0; it < 8; ++it) {
        int idx = it * 256 + t;
        int row = idx >> 4, c = idx & 15;
        uint4 v = *(const uint4*)&WT[row * 128 + c * 8];
        int byte = (row * 256 + c * 16) ^ ((row & 7) << 4);
        *(uint4*)((char*)w_lds + byte) = v;
    }
    #pragma unroll
    for (int it = 0; it < 4; ++it) {
        int idx = it * 256 + t;
        int row = idx >> 4, c = idx & 15;
        int grow = m0 + row;
        float4 v0 = make_float4(0.f, 0.f, 0.f, 0.f), v1 = v0;
        if (grow < n) {
            v0 = *(const float4*)&A[(size_t)grow * D + c * 8];
            v1 = *(const float4*)&A[(size_t)grow * D + c * 8 + 4];
        }
        uint2 lo, hi;
        lo.x = (unsigned)f2bf(v0.x) | ((unsigned)f2bf(v0.y) << 16);
        lo.y = (unsigned)f2bf(v0.z) | ((unsigned)f2bf(v0.w) << 16);
        hi.x = (unsigned)f2bf(v1.x) | ((unsigned)f2bf(v1.y) << 16);
        hi.y = (unsigned)f2bf(v1.z) | ((unsigned)f2bf(v1.w) << 16);
        int byte = (row * 256 + c * 16) ^ ((row & 7) << 4);
        *(uint4*)((char*)a_lds + byte) = make_uint4(lo.x, lo.y, hi.x, hi.y);
    }
    __syncthreads();

    int wv = t >> 6, l = t & 63;
    int lrow = l & 15, lgrp = l >> 4;
    int arow = wv * 16 + lrow;

    f32x4 acc[8];
    #pragma unroll
    for (int nf = 0; nf < 8; ++nf) acc[nf] = (f32x4){0.f, 0.f, 0.f, 0.f};

    #pragma unroll
    for (int kk = 0; kk < 4; ++kk) {
        int abyte = (arow * 256 + kk * 64 + lgrp * 16) ^ ((arow & 7) << 4);
        bf16x8 afrag = *(bf16x8*)((char*)a_lds + abyte);
        #pragma unroll
        for (int nf = 0; nf < 8; ++nf) {
            int bcol = nf * 16 + lrow;
            int bbyte = (bcol * 256 + kk * 64 + lgrp * 16) ^ ((bcol & 7) << 4);
            bf16x8 bfrag = *(bf16x8*)((char*)w_lds + bbyte);
            acc[nf] = __builtin_amdgcn_mfma_f32_16x16x32_bf16(afrag, bfrag, acc[nf], 0, 0, 0);
        }
    }

    #pragma unroll
    for (int nf = 0; nf < 8; ++nf) {
        #pragma unroll
        for (int r = 0; r < 4; ++r) {
            int grow = m0 + wv * 16 + lgrp * 4 + r;
            if (grow < n) {
                int col = nf * 16 + lrow;
                out[(size_t)grow * D + col] = f2bf(acc[nf][r]);
            }
        }
    }
}

// ---------------- fused aggregate + bias + (leaky) + residual + LayerNorm ----------------
// Wave-per-node; edge runs padded to multiple of 8 -> no remainder loop.
template <int MODE>
__global__ __launch_bounds__(256) void agg_ln(const unsigned* __restrict__ h,  // bf16x2 per dword
                                              const float* __restrict__ x,
                                              const float* __restrict__ bias,
                                              const float* __restrict__ gamma,
                                              const float* __restrict__ beta,
                                              const float* __restrict__ dinv,
                                              const int* __restrict__ rowstart,
                                              const int2* __restrict__ csr_pair,
                                              float* __restrict__ out) {
    int wid = threadIdx.x >> 6;
    int lane = threadIdx.x & 63;
    int i = blockIdx.x * 4 + wid;   // NN = 50000 = 12500 * 4, exact
    float di = dinv[i];
    size_t rowoff = (size_t)i * D + 2 * lane;

    float hx, hy;
    bf2x(h[(size_t)i * (D / 2) + lane], hx, hy);
    float accx = di * di * hx, accy = di * di * hy;

    int e = __builtin_amdgcn_readfirstlane(rowstart[i]);
    int e1 = __builtin_amdgcn_readfirstlane(rowstart[i + 1]);

    for (; e < e1; e += 8) {
        int4 q0 = *(const int4*)&csr_pair[e + 0];
        int4 q1 = *(const int4*)&csr_pair[e + 2];
        int4 q2 = *(const int4*)&csr_pair[e + 4];
        int4 q3 = *(const int4*)&csr_pair[e + 6];
        unsigned g0 = h[(size_t)q0.x * (D / 2) + lane];
        unsigned g1 = h[(size_t)q0.z * (D / 2) + lane];
        unsigned g2 = h[(size_t)q1.x * (D / 2) + lane];
        unsigned g3 = h[(size_t)q1.z * (D / 2) + lane];
        unsigned g4 = h[(size_t)q2.x * (D / 2) + lane];
        unsigned g5 = h[(size_t)q2.z * (D / 2) + lane];
        unsigned g6 = h[(size_t)q3.x * (D / 2) + lane];
        unsigned g7 = h[(size_t)q3.z * (D / 2) + lane];
        float ax, ay, c;
        c = __int_as_float(q0.y); bf2x(g0, ax, ay); accx = fmaf(c, ax, accx); accy = fmaf(c, ay, accy);
        c = __int_as_float(q0.w); bf2x(g1, ax, ay); accx = fmaf(c, ax, accx); accy = fmaf(c, ay, accy);
        c = __int_as_float(q1.y); bf2x(g2, ax, ay); accx = fmaf(c, ax, accx); accy = fmaf(c, ay, accy);
        c = __int_as_float(q1.w); bf2x(g3, ax, ay); accx = fmaf(c, ax, accx); accy = fmaf(c, ay, accy);
        c = __int_as_float(q2.y); bf2x(g4, ax, ay); accx = fmaf(c, ax, accx); accy = fmaf(c, ay, accy);
        c = __int_as_float(q2.w); bf2x(g5, ax, ay); accx = fmaf(c, ax, accx); accy = fmaf(c, ay, accy);
        c = __int_as_float(q3.y); bf2x(g6, ax, ay); accx = fmaf(c, ax, accx); accy = fmaf(c, ay, accy);
        c = __int_as_float(q3.w); bf2x(g7, ax, ay); accx = fmaf(c, ax, accx); accy = fmaf(c, ay, accy);
    }

    float2 bv = *(const float2*)&bias[2 * lane];
    accx += bv.x; accy += bv.y;
    if (MODE == 0) {
        accx = accx > 0.f ? accx : NEG_SLOPE * accx;
        accy = accy > 0.f ? accy : NEG_SLOPE * accy;
    }
    float2 xv = *(const float2*)&x[rowoff];
    float v0 = accx + xv.x, v1 = accy + xv.y;

    float s1 = v0 + v1, s2 = v0 * v0 + v1 * v1;
    #pragma unroll
    for (int off = 1; off < 64; off <<= 1) {
        s1 += __shfl_xor(s1, off, 64);
        s2 += __shfl_xor(s2, off, 64);
    }
    float mu = s1 * (1.f / 128.f);
    float var = fmaxf(s2 * (1.f / 128.f) - mu * mu, 0.f);
    float rs = rsqrtf(var + LN_EPS);

    float2 gv = *(const float2*)&gamma[2 * lane];
    float2 bt = *(const float2*)&beta[2 * lane];
    float o0 = (v0 - mu) * rs * gv.x + bt.x;
    float o1 = (v1 - mu) * rs * gv.y + bt.y;
    if (MODE == 1) {
        o0 = o0 > 0.f ? o0 : NEG_SLOPE * o0;
        o1 = o1 > 0.f ? o1 : NEG_SLOPE * o1;
    }
    *(float2*)&out[rowoff] = make_float2(o0, o1);
}

extern "C" void kernel_launch(void* const* d_in, const int* in_sizes, int n_in,
                              void* d_out, int out_size, void* d_ws, size_t ws_size,
                              hipStream_t stream) {
    const float* x    = (const float*)d_in[0];
    const int*   ei   = (const int*)d_in[1];   // [2, NE]: row0 src, row1 dst
    const float* W1   = (const float*)d_in[2];
    const float* b1   = (const float*)d_in[3];
    const float* ln1g = (const float*)d_in[4];
    const float* ln1b = (const float*)d_in[5];
    const float* W2   = (const float*)d_in[6];
    const float* b2   = (const float*)d_in[7];
    const float* ln2g = (const float*)d_in[8];
    const float* ln2b = (const float*)d_in[9];
    float* out = (float*)d_out;

    const int* srcp = ei;
    const int* dstp = ei + NE;

    char* ws = (char*)d_ws;
    size_t p = 0;
    auto alloc = [&](size_t bytes) {
        char* r = ws + p;
        p += (bytes + 255) & ~(size_t)255;
        return r;
    };
    int*   bcount   = (int*)alloc(NB * 4);          // zeroed together (adjacent,
    int*   bcursor  = (int*)alloc(NB * 4);          //  each padded to 1024 B)
    int*   bstart   = (int*)alloc((NB + 1) * 4);
    int*   pbsum    = (int*)alloc(NB * 4);
    int*   pbstart  = (int*)alloc(NB * 4);
    int*   prowtmp  = (int*)alloc(NB * NPB * 4);
    int*   rowstart = (int*)alloc((NN + 1) * 4);
    float* dinv     = (float*)alloc(NN * 4);
    int2*  bedge    = (int2*)alloc((size_t)NE * 8);
    int2*  csr_pair = (int2*)alloc(((size_t)NE + 8 * NN) * 8);  // padded CSR
    unsigned short* hbf = (unsigned short*)alloc((size_t)NN * D * 2);
    unsigned short* wt1 = (unsigned short*)alloc(D * D * 2);
    unsigned short* wt2 = (unsigned short*)alloc(D * D * 2);

    hipMemsetAsync(bcount, 0, 2048, stream);   // covers bcount + bcursor

    bucket_count<<<NCH, 256, 0, stream>>>(dstp, bcount, NE);
    bucket_scan<<<1, 256, 0, stream>>>(bcount, bstart);
    bucket_scatter<<<NCH, 256, 0, stream>>>(srcp, dstp, bstart, bcursor, bedge, NE);
    node_count<<<NB, 256, 0, stream>>>(bedge, bstart, dinv, prowtmp, pbsum);
    pbucket_scan<<<1, 256, 0, stream>>>(pbsum, pbstart, &rowstart[NN]);
    csr_scatter<<<NB, 256, 0, stream>>>(bedge, bstart, pbstart, prowtmp, dinv,
                                        rowstart, csr_pair);

    wt_pack2<<<2 * D * D / 256, 256, 0, stream>>>(W1, W2, wt1, wt2);

    // Layer 1: h1 = bf16(x @ W1) ; out = LN1(leaky(agg(h1)+b1) + x)
    gemm_mfma<<<(NN + 63) / 64, 256, 0, stream>>>(x, wt1, hbf, NN);
    agg_ln<0><<<NN / 4, 256, 0, stream>>>((const unsigned*)hbf, x, b1, ln1g, ln1b, dinv,
                                          rowstart, csr_pair, out);

    // Layer 2: t = bf16(out @ W2) ; out = leaky(LN2(agg(t)+b2 + x))
    gemm_mfma<<<(NN + 63) / 64, 256, 0, stream>>>(out, wt2, hbf, NN);
    agg_ln<1><<<NN / 4, 256, 0, stream>>>((const unsigned*)hbf, x, b2, ln2g, ln2b, dinv,
                                          rowstart, csr_pair, out);
}

// Round 7
// 147.385 us; speedup vs baseline: 2.4017x; 1.1137x over previous
//
#include <hip/hip_runtime.h>
#include <hip/hip_bf16.h>

#define NN 50000
#define NE 800000
#define D 128
#define NEG_SLOPE 0.01f
#define LN_EPS 1e-5f

#define NPB 256                 // nodes per bucket (bucket = dst >> 8)
#define NB 196                  // ceil(NN / NPB); NB*256 = 50176
#define CAP 6144                // per-bucket bedge capacity (avg 4082, max ~4340)
#define ECH 8192                // edges per workgroup in bucket pass
#define NCH ((NE + ECH - 1) / ECH)  // 98

typedef __attribute__((ext_vector_type(8))) short bf16x8;
typedef __attribute__((ext_vector_type(4))) float f32x4;

// f32 -> bf16 round-to-nearest-even (finite values)
__device__ inline unsigned short f2bf(float f) {
    unsigned u = __float_as_uint(f);
    unsigned r = 0x7FFFu + ((u >> 16) & 1u);
    return (unsigned short)((u + r) >> 16);
}
// unpack one dword = 2 bf16 -> 2 floats
__device__ inline void bf2x(unsigned u, float& lo, float& hi) {
    lo = __uint_as_float(u << 16);
    hi = __uint_as_float(u & 0xFFFF0000u);
}

// ---------------- bucket-sorted CSR build (no random global scatter) ----------------

// LDS-binned scatter of (src,dst) into fixed-capacity bucket regions of bedge.
// Per-bucket global ranges reserved with one atomic per bucket; contiguous runs
// flushed -> mostly full-cacheline global writes. No count/scan pre-pass needed.
__global__ __launch_bounds__(256) void bucket_scatter(const int* __restrict__ src,
                                                      const int* __restrict__ dst,
                                                      int* __restrict__ bcursor,
                                                      int2* __restrict__ bedge, int ne) {
    __shared__ int2 stage[ECH];                      // 64 KB
    __shared__ int hist[NB], lofs[NB], lcur[NB], gbase[NB];
    __shared__ int tmp[256];
    int t = threadIdx.x;
    int e0 = blockIdx.x * ECH;
    int ecnt = min(ECH, ne - e0);
    if (t < NB) hist[t] = 0;
    __syncthreads();
    for (int k = t; k < ecnt; k += 256) atomicAdd(&hist[dst[e0 + k] >> 8], 1);
    __syncthreads();
    int v = (t < NB) ? hist[t] : 0;
    tmp[t] = v;
    __syncthreads();
    for (int off = 1; off < 256; off <<= 1) {
        int u = (t >= off) ? tmp[t - off] : 0;
        __syncthreads();
        tmp[t] += u;
        __syncthreads();
    }
    if (t < NB) {
        lofs[t] = tmp[t] - v;
        lcur[t] = tmp[t] - v;
        gbase[t] = atomicAdd(&bcursor[t], v);        // reserve global run
    }
    __syncthreads();
    for (int k = t; k < ecnt; k += 256) {
        int s = src[e0 + k], d = dst[e0 + k];
        int p = atomicAdd(&lcur[d >> 8], 1);
        stage[p] = make_int2(s, d);
    }
    __syncthreads();
    for (int k = t; k < ecnt; k += 256) {
        int2 eg = stage[k];
        int b = eg.y >> 8;
        bedge[(size_t)b * CAP + gbase[b] + (k - lofs[b])] = eg;
    }
}

// Per-bucket node histogram -> dinv + local exclusive scan of PADDED degrees
// (padded to multiple of 8) + per-bucket padded total.
__global__ __launch_bounds__(256) void node_count(const int2* __restrict__ bedge,
                                                  const int* __restrict__ bcnt,
                                                  float* __restrict__ dinv,
                                                  int* __restrict__ prowtmp,
                                                  int* __restrict__ pbsum) {
    __shared__ int h[NPB];
    __shared__ int tmp[256];
    int b = blockIdx.x, t = threadIdx.x;
    h[t] = 0;
    __syncthreads();
    int s0 = b * CAP, s1 = s0 + bcnt[b];
    for (int k = s0 + t; k < s1; k += 256) atomicAdd(&h[bedge[k].y & 255], 1);
    __syncthreads();
    int deg = h[t];
    int node = b * NPB + t;
    if (node < NN) dinv[node] = rsqrtf((float)(deg + 1));   // +1: self-loop
    int pdeg = (deg + 7) & ~7;                              // pad to multiple of 8
    tmp[t] = pdeg;
    __syncthreads();
    for (int off = 1; off < 256; off <<= 1) {
        int u = (t >= off) ? tmp[t - off] : 0;
        __syncthreads();
        tmp[t] += u;
        __syncthreads();
    }
    prowtmp[b * NPB + t] = tmp[t] - pdeg;
    if (t == 255) pbsum[b] = tmp[255];
}

// Scan padded bucket totals; writes rowstart[NN] = padded grand total.
__global__ void pbucket_scan(const int* __restrict__ pbsum, int* __restrict__ pbstart,
                             int* __restrict__ rowstart_nn) {
    __shared__ int tmp[256];
    int t = threadIdx.x;
    int v = (t < NB) ? pbsum[t] : 0;
    tmp[t] = v;
    __syncthreads();
    for (int off = 1; off < 256; off <<= 1) {
        int u = (t >= off) ? tmp[t - off] : 0;
        __syncthreads();
        tmp[t] += u;
        __syncthreads();
    }
    if (t < NB) pbstart[t] = tmp[t] - v;
    if (t == 255) *rowstart_nn = tmp[255];
}

// Per-bucket scatter into padded CSR; writes rowstart and pads each node's run
// to a multiple of 8 with (self, coef=0) dummy edges (cache-hot, zero effect).
__global__ __launch_bounds__(256) void csr_scatter(const int2* __restrict__ bedge,
                                                   const int* __restrict__ bcnt,
                                                   const int* __restrict__ pbstart,
                                                   const int* __restrict__ prowtmp,
                                                   const float* __restrict__ dinv,
                                                   int* __restrict__ rowstart,
                                                   int2* __restrict__ csr_pair) {
    __shared__ int cur[NPB];
    __shared__ int rl[NPB];
    int b = blockIdx.x, t = threadIdx.x;
    int base = pbstart[b];
    int node = b * NPB + t;
    int r = base + prowtmp[node];
    rl[t] = r;
    cur[t] = 0;
    if (node < NN) rowstart[node] = r;
    __syncthreads();
    int s0 = b * CAP, s1 = s0 + bcnt[b];
    for (int k = s0 + t; k < s1; k += 256) {
        int2 eg = bedge[k];
        int li = eg.y & 255;
        int p = atomicAdd(&cur[li], 1);
        float coef = dinv[eg.x] * dinv[eg.y];
        csr_pair[rl[li] + p] = make_int2(eg.x, __float_as_int(coef));
    }
    __syncthreads();
    int deg = cur[t];
    int pend = (deg + 7) & ~7;
    int selfsrc = (node < NN) ? node : 0;
    for (int k = deg; k < pend; ++k)
        csr_pair[rl[t] + k] = make_int2(selfsrc, 0);
}

// Pack W1 and W2 (f32 [k][n]) -> bf16 [n][k] in ONE launch.
__global__ void wt_pack2(const float* __restrict__ W1, const float* __restrict__ W2,
                         unsigned short* __restrict__ WT1, unsigned short* __restrict__ WT2) {
    int tid = blockIdx.x * 256 + threadIdx.x;      // 2 * 16384 threads
    const float* W = (tid < D * D) ? W1 : W2;
    unsigned short* WT = (tid < D * D) ? WT1 : WT2;
    int id = tid & (D * D - 1);
    int nn = id & 127, k = id >> 7;
    WT[nn * 128 + k] = f2bf(W[k * 128 + nn]);
}

// ---------------- MFMA GEMM: out_bf16[n x 128] = bf16(A[n x 128]) @ WT^T ----------------
__global__ __launch_bounds__(256) void gemm_mfma(const float* __restrict__ A,
                                                 const unsigned short* __restrict__ WT,
                                                 unsigned short* __restrict__ out, int n) {
    __shared__ __align__(16) unsigned short a_lds[64 * 128];   // 16 KB
    __shared__ __align__(16) unsigned short w_lds[128 * 128];  // 32 KB
    int t = threadIdx.x;
    int m0 = blockIdx.x * 64;

    #pragma unroll
    for (int it = 0; it < 8; ++it) {
        int idx = it * 256 + t;
        int row = idx >> 4, c = idx & 15;
        uint4 v = *(const uint4*)&WT[row * 128 + c * 8];
        int byte = (row * 256 + c * 16) ^ ((row & 7) << 4);
        *(uint4*)((char*)w_lds + byte) = v;
    }
    #pragma unroll
    for (int it = 0; it < 4; ++it) {
        int idx = it * 256 + t;
        int row = idx >> 4, c = idx & 15;
        int grow = m0 + row;
        float4 v0 = make_float4(0.f, 0.f, 0.f, 0.f), v1 = v0;
        if (grow < n) {
            v0 = *(const float4*)&A[(size_t)grow * D + c * 8];
            v1 = *(const float4*)&A[(size_t)grow * D + c * 8 + 4];
        }
        uint2 lo, hi;
        lo.x = (unsigned)f2bf(v0.x) | ((unsigned)f2bf(v0.y) << 16);
        lo.y = (unsigned)f2bf(v0.z) | ((unsigned)f2bf(v0.w) << 16);
        hi.x = (unsigned)f2bf(v1.x) | ((unsigned)f2bf(v1.y) << 16);
        hi.y = (unsigned)f2bf(v1.z) | ((unsigned)f2bf(v1.w) << 16);
        int byte = (row * 256 + c * 16) ^ ((row & 7) << 4);
        *(uint4*)((char*)a_lds + byte) = make_uint4(lo.x, lo.y, hi.x, hi.y);
    }
    __syncthreads();

    int wv = t >> 6, l = t & 63;
    int lrow = l & 15, lgrp = l >> 4;
    int arow = wv * 16 + lrow;

    f32x4 acc[8];
    #pragma unroll
    for (int nf = 0; nf < 8; ++nf) acc[nf] = (f32x4){0.f, 0.f, 0.f, 0.f};

    #pragma unroll
    for (int kk = 0; kk < 4; ++kk) {
        int abyte = (arow * 256 + kk * 64 + lgrp * 16) ^ ((arow & 7) << 4);
        bf16x8 afrag = *(bf16x8*)((char*)a_lds + abyte);
        #pragma unroll
        for (int nf = 0; nf < 8; ++nf) {
            int bcol = nf * 16 + lrow;
            int bbyte = (bcol * 256 + kk * 64 + lgrp * 16) ^ ((bcol & 7) << 4);
            bf16x8 bfrag = *(bf16x8*)((char*)w_lds + bbyte);
            acc[nf] = __builtin_amdgcn_mfma_f32_16x16x32_bf16(afrag, bfrag, acc[nf], 0, 0, 0);
        }
    }

    #pragma unroll
    for (int nf = 0; nf < 8; ++nf) {
        #pragma unroll
        for (int r = 0; r < 4; ++r) {
            int grow = m0 + wv * 16 + lgrp * 4 + r;
            if (grow < n) {
                int col = nf * 16 + lrow;
                out[(size_t)grow * D + col] = f2bf(acc[nf][r]);
            }
        }
    }
}

// ---------------- fused aggregate + bias + (leaky) + residual + LayerNorm ----------------

// one 8-edge block: 4 pair-loads + 8 gathers + 16 fma
__device__ inline void agg8(const unsigned* __restrict__ h, const int2* __restrict__ csr_pair,
                            int e, int lane, float& accx, float& accy) {
    int4 q0 = *(const int4*)&csr_pair[e + 0];
    int4 q1 = *(const int4*)&csr_pair[e + 2];
    int4 q2 = *(const int4*)&csr_pair[e + 4];
    int4 q3 = *(const int4*)&csr_pair[e + 6];
    unsigned g0 = h[(size_t)q0.x * (D / 2) + lane];
    unsigned g1 = h[(size_t)q0.z * (D / 2) + lane];
    unsigned g2 = h[(size_t)q1.x * (D / 2) + lane];
    unsigned g3 = h[(size_t)q1.z * (D / 2) + lane];
    unsigned g4 = h[(size_t)q2.x * (D / 2) + lane];
    unsigned g5 = h[(size_t)q2.z * (D / 2) + lane];
    unsigned g6 = h[(size_t)q3.x * (D / 2) + lane];
    unsigned g7 = h[(size_t)q3.z * (D / 2) + lane];
    float ax, ay, c;
    c = __int_as_float(q0.y); bf2x(g0, ax, ay); accx = fmaf(c, ax, accx); accy = fmaf(c, ay, accy);
    c = __int_as_float(q0.w); bf2x(g1, ax, ay); accx = fmaf(c, ax, accx); accy = fmaf(c, ay, accy);
    c = __int_as_float(q1.y); bf2x(g2, ax, ay); accx = fmaf(c, ax, accx); accy = fmaf(c, ay, accy);
    c = __int_as_float(q1.w); bf2x(g3, ax, ay); accx = fmaf(c, ax, accx); accy = fmaf(c, ay, accy);
    c = __int_as_float(q2.y); bf2x(g4, ax, ay); accx = fmaf(c, ax, accx); accy = fmaf(c, ay, accy);
    c = __int_as_float(q2.w); bf2x(g5, ax, ay); accx = fmaf(c, ax, accx); accy = fmaf(c, ay, accy);
    c = __int_as_float(q3.y); bf2x(g6, ax, ay); accx = fmaf(c, ax, accx); accy = fmaf(c, ay, accy);
    c = __int_as_float(q3.w); bf2x(g7, ax, ay); accx = fmaf(c, ax, accx); accy = fmaf(c, ay, accy);
}

template <int MODE>
__device__ inline float2 ln_norm(float v0, float v1, float2 gv, float2 bt) {
    float s1 = v0 + v1, s2 = v0 * v0 + v1 * v1;
    #pragma unroll
    for (int off = 1; off < 64; off <<= 1) {
        s1 += __shfl_xor(s1, off, 64);
        s2 += __shfl_xor(s2, off, 64);
    }
    float mu = s1 * (1.f / 128.f);
    float var = fmaxf(s2 * (1.f / 128.f) - mu * mu, 0.f);
    float rs = rsqrtf(var + LN_EPS);
    float o0 = (v0 - mu) * rs * gv.x + bt.x;
    float o1 = (v1 - mu) * rs * gv.y + bt.y;
    if (MODE == 1) {
        o0 = o0 > 0.f ? o0 : NEG_SLOPE * o0;
        o1 = o1 > 0.f ? o1 : NEG_SLOPE * o1;
    }
    return make_float2(o0, o1);
}

// TWO nodes per wave, 8+8 joint unroll -> 16 gathers in flight.
// Edge runs padded to multiple of 8 -> drains are exact, no remainder.
// MODE 0: out = LN1(leaky(agg + b1) + x);  MODE 1: out = leaky(LN2(agg + b2 + x))
template <int MODE>
__global__ __launch_bounds__(256) void agg_ln(const unsigned* __restrict__ h,  // bf16x2 per dword
                                              const float* __restrict__ x,
                                              const float* __restrict__ bias,
                                              const float* __restrict__ gamma,
                                              const float* __restrict__ beta,
                                              const float* __restrict__ dinv,
                                              const int* __restrict__ rowstart,
                                              const int2* __restrict__ csr_pair,
                                              float* __restrict__ out) {
    int wid = threadIdx.x >> 6;
    int lane = threadIdx.x & 63;
    int iA = blockIdx.x * 8 + wid * 2;   // NN = 50000 = 6250 * 8, exact
    int iB = iA + 1;
    float diA = dinv[iA], diB = dinv[iB];
    size_t rowA = (size_t)iA * D + 2 * lane;
    size_t rowB = (size_t)iB * D + 2 * lane;

    float hx, hy;
    bf2x(h[(size_t)iA * (D / 2) + lane], hx, hy);
    float aAx = diA * diA * hx, aAy = diA * diA * hy;
    bf2x(h[(size_t)iB * (D / 2) + lane], hx, hy);
    float aBx = diB * diB * hx, aBy = diB * diB * hy;

    int eA = __builtin_amdgcn_readfirstlane(rowstart[iA]);
    int eA1 = __builtin_amdgcn_readfirstlane(rowstart[iA + 1]);
    int eB = __builtin_amdgcn_readfirstlane(rowstart[iB]);
    int eB1 = __builtin_amdgcn_readfirstlane(rowstart[iB + 1]);

    // joint loop: 16 gathers in flight
    while (eA < eA1 && eB < eB1) {
        int4 qA0 = *(const int4*)&csr_pair[eA + 0];
        int4 qA1 = *(const int4*)&csr_pair[eA + 2];
        int4 qA2 = *(const int4*)&csr_pair[eA + 4];
        int4 qA3 = *(const int4*)&csr_pair[eA + 6];
        int4 qB0 = *(const int4*)&csr_pair[eB + 0];
        int4 qB1 = *(const int4*)&csr_pair[eB + 2];
        int4 qB2 = *(const int4*)&csr_pair[eB + 4];
        int4 qB3 = *(const int4*)&csr_pair[eB + 6];
        unsigned gA0 = h[(size_t)qA0.x * (D / 2) + lane];
        unsigned gA1 = h[(size_t)qA0.z * (D / 2) + lane];
        unsigned gA2 = h[(size_t)qA1.x * (D / 2) + lane];
        unsigned gA3 = h[(size_t)qA1.z * (D / 2) + lane];
        unsigned gA4 = h[(size_t)qA2.x * (D / 2) + lane];
        unsigned gA5 = h[(size_t)qA2.z * (D / 2) + lane];
        unsigned gA6 = h[(size_t)qA3.x * (D / 2) + lane];
        unsigned gA7 = h[(size_t)qA3.z * (D / 2) + lane];
        unsigned gB0 = h[(size_t)qB0.x * (D / 2) + lane];
        unsigned gB1 = h[(size_t)qB0.z * (D / 2) + lane];
        unsigned gB2 = h[(size_t)qB1.x * (D / 2) + lane];
        unsigned gB3 = h[(size_t)qB1.z * (D / 2) + lane];
        unsigned gB4 = h[(size_t)qB2.x * (D / 2) + lane];
        unsigned gB5 = h[(size_t)qB2.z * (D / 2) + lane];
        unsigned gB6 = h[(size_t)qB3.x * (D / 2) + lane];
        unsigned gB7 = h[(size_t)qB3.z * (D / 2) + lane];
        float ax, ay, c;
        c = __int_as_float(qA0.y); bf2x(gA0, ax, ay); aAx = fmaf(c, ax, aAx); aAy = fmaf(c, ay, aAy);
        c = __int_as_float(qA0.w); bf2x(gA1, ax, ay); aAx = fmaf(c, ax, aAx); aAy = fmaf(c, ay, aAy);
        c = __int_as_float(qA1.y); bf2x(gA2, ax, ay); aAx = fmaf(c, ax, aAx); aAy = fmaf(c, ay, aAy);
        c = __int_as_float(qA1.w); bf2x(gA3, ax, ay); aAx = fmaf(c, ax, aAx); aAy = fmaf(c, ay, aAy);
        c = __int_as_float(qA2.y); bf2x(gA4, ax, ay); aAx = fmaf(c, ax, aAx); aAy = fmaf(c, ay, aAy);
        c = __int_as_float(qA2.w); bf2x(gA5, ax, ay); aAx = fmaf(c, ax, aAx); aAy = fmaf(c, ay, aAy);
        c = __int_as_float(qA3.y); bf2x(gA6, ax, ay); aAx = fmaf(c, ax, aAx); aAy = fmaf(c, ay, aAy);
        c = __int_as_float(qA3.w); bf2x(gA7, ax, ay); aAx = fmaf(c, ax, aAx); aAy = fmaf(c, ay, aAy);
        c = __int_as_float(qB0.y); bf2x(gB0, ax, ay); aBx = fmaf(c, ax, aBx); aBy = fmaf(c, ay, aBy);
        c = __int_as_float(qB0.w); bf2x(gB1, ax, ay); aBx = fmaf(c, ax, aBx); aBy = fmaf(c, ay, aBy);
        c = __int_as_float(qB1.y); bf2x(gB2, ax, ay); aBx = fmaf(c, ax, aBx); aBy = fmaf(c, ay, aBy);
        c = __int_as_float(qB1.w); bf2x(gB3, ax, ay); aBx = fmaf(c, ax, aBx); aBy = fmaf(c, ay, aBy);
        c = __int_as_float(qB2.y); bf2x(gB4, ax, ay); aBx = fmaf(c, ax, aBx); aBy = fmaf(c, ay, aBy);
        c = __int_as_float(qB2.w); bf2x(gB5, ax, ay); aBx = fmaf(c, ax, aBx); aBy = fmaf(c, ay, aBy);
        c = __int_as_float(qB3.y); bf2x(gB6, ax, ay); aBx = fmaf(c, ax, aBx); aBy = fmaf(c, ay, aBy);
        c = __int_as_float(qB3.w); bf2x(gB7, ax, ay); aBx = fmaf(c, ax, aBx); aBy = fmaf(c, ay, aBy);
        eA += 8; eB += 8;
    }
    while (eA < eA1) { agg8(h, csr_pair, eA, lane, aAx, aAy); eA += 8; }
    while (eB < eB1) { agg8(h, csr_pair, eB, lane, aBx, aBy); eB += 8; }

    float2 bv = *(const float2*)&bias[2 * lane];
    float2 gv = *(const float2*)&gamma[2 * lane];
    float2 bt = *(const float2*)&beta[2 * lane];

    aAx += bv.x; aAy += bv.y;
    aBx += bv.x; aBy += bv.y;
    if (MODE == 0) {
        aAx = aAx > 0.f ? aAx : NEG_SLOPE * aAx;
        aAy = aAy > 0.f ? aAy : NEG_SLOPE * aAy;
        aBx = aBx > 0.f ? aBx : NEG_SLOPE * aBx;
        aBy = aBy > 0.f ? aBy : NEG_SLOPE * aBy;
    }
    float2 xA = *(const float2*)&x[rowA];
    float2 xB = *(const float2*)&x[rowB];

    float2 oA = ln_norm<MODE>(aAx + xA.x, aAy + xA.y, gv, bt);
    float2 oB = ln_norm<MODE>(aBx + xB.x, aBy + xB.y, gv, bt);
    *(float2*)&out[rowA] = oA;
    *(float2*)&out[rowB] = oB;
}

extern "C" void kernel_launch(void* const* d_in, const int* in_sizes, int n_in,
                              void* d_out, int out_size, void* d_ws, size_t ws_size,
                              hipStream_t stream) {
    const float* x    = (const float*)d_in[0];
    const int*   ei   = (const int*)d_in[1];   // [2, NE]: row0 src, row1 dst
    const float* W1   = (const float*)d_in[2];
    const float* b1   = (const float*)d_in[3];
    const float* ln1g = (const float*)d_in[4];
    const float* ln1b = (const float*)d_in[5];
    const float* W2   = (const float*)d_in[6];
    const float* b2   = (const float*)d_in[7];
    const float* ln2g = (const float*)d_in[8];
    const float* ln2b = (const float*)d_in[9];
    float* out = (float*)d_out;

    const int* srcp = ei;
    const int* dstp = ei + NE;

    char* ws = (char*)d_ws;
    size_t p = 0;
    auto alloc = [&](size_t bytes) {
        char* r = ws + p;
        p += (bytes + 255) & ~(size_t)255;
        return r;
    };
    int*   bcursor  = (int*)alloc(NB * 4);
    int*   pbsum    = (int*)alloc(NB * 4);
    int*   pbstart  = (int*)alloc(NB * 4);
    int*   prowtmp  = (int*)alloc(NB * NPB * 4);
    int*   rowstart = (int*)alloc((NN + 1) * 4);
    float* dinv     = (float*)alloc(NN * 4);
    int2*  bedge    = (int2*)alloc((size_t)NB * CAP * 8);
    int2*  csr_pair = (int2*)alloc(((size_t)NE + 8 * NN) * 8);  // padded CSR
    unsigned short* hbf = (unsigned short*)alloc((size_t)NN * D * 2);
    unsigned short* wt1 = (unsigned short*)alloc(D * D * 2);
    unsigned short* wt2 = (unsigned short*)alloc(D * D * 2);

    hipMemsetAsync(bcursor, 0, NB * 4, stream);

    bucket_scatter<<<NCH, 256, 0, stream>>>(srcp, dstp, bcursor, bedge, NE);
    node_count<<<NB, 256, 0, stream>>>(bedge, bcursor, dinv, prowtmp, pbsum);
    pbucket_scan<<<1, 256, 0, stream>>>(pbsum, pbstart, &rowstart[NN]);
    csr_scatter<<<NB, 256, 0, stream>>>(bedge, bcursor, pbstart, prowtmp, dinv,
                                        rowstart, csr_pair);

    wt_pack2<<<2 * D * D / 256, 256, 0, stream>>>(W1, W2, wt1, wt2);

    // Layer 1: h1 = bf16(x @ W1) ; out = LN1(leaky(agg(h1)+b1) + x)
    gemm_mfma<<<(NN + 63) / 64, 256, 0, stream>>>(x, wt1, hbf, NN);
    agg_ln<0><<<NN / 8, 256, 0, stream>>>((const unsigned*)hbf, x, b1, ln1g, ln1b, dinv,
                                          rowstart, csr_pair, out);

    // Layer 2: t = bf16(out @ W2) ; out = leaky(LN2(agg(t)+b2 + x))
    gemm_mfma<<<(NN + 63) / 64, 256, 0, stream>>>(out, wt2, hbf, NN);
    agg_ln<1><<<NN / 8, 256, 0, stream>>>((const unsigned*)hbf, x, b2, ln2g, ln2b, dinv,
                                          rowstart, csr_pair, out);
}